// Round 3
// baseline (201.190 us; speedup 1.0000x reference)
//
#include <hip/hip_runtime.h>

#define NN    100000   // N_NODES
#define F     64       // feature dim (= hidden dim)
#define NBUCK 391      // ceil(NN/256) buckets of 256 nodes
#define CAPB  4096     // per-bucket edge capacity (mean 3197, 16-sigma margin)
#define TILE  4096     // edges per binpack tile
#define G1A   1600     // gemm1 blocks placed in K1 (rest overlap node_sort in K2)
#define G1TOT 3125     // NN/32 total gemm1 blocks

// workspace offsets (4-byte elements)
#define O_CURSOR 0          // int[391]
#define O_ROWPTR 512        // int[100000]  absolute index into srt
#define O_DEG    100864     // int[100000]
#define O_DIS    201216     // float[100000]
#define O_PACKED 301568     // uint[391*4096]
#define O_SRT    1903104    // int[391*4096 + 64]
#define O_AH     3504768    // uint[NN*32]: bf16-packed layer-1 A rows (128 B/row)
#define O_BH     6704768    // uint[NN*32]: bf16-packed layer-2 rows dis*(h@W2)

typedef __attribute__((ext_vector_type(8))) short bf16x8;
typedef __attribute__((ext_vector_type(4))) float f32x4;

// ---- bf16 pack/unpack (RNE; values finite) --------------------------------
__device__ __forceinline__ unsigned bf_rne(float x) {
    unsigned u = __float_as_uint(x);
    return (u + 0x7FFFu + ((u >> 16) & 1u)) >> 16;
}
__device__ __forceinline__ unsigned pack2(float lo, float hi) {
    return bf_rne(lo) | (bf_rne(hi) << 16);
}
__device__ __forceinline__ float lo_f(unsigned u) { return __uint_as_float(u << 16); }
__device__ __forceinline__ float hi_f(unsigned u) { return __uint_as_float(u & 0xFFFF0000u); }

// ---- shared-memory unions (per-block exclusive) ----------------------------
struct BpSmem {
    int hist[NBUCK], lofs[NBUCK], gbase[NBUCK], lcur[NBUCK];
    int wsum[8];
    unsigned stage[TILE];                     // 16 KB
    unsigned short sbuck[TILE];               // 8 KB
};                                            // 30864 B
union KSmem {
    BpSmem bp;
    float wl[64 * 64];                        // 16 KB
};
struct NsSmem {
    int h[256], lcur[256], wsum[4];
    int stage[CAPB];                          // 16 KB
};                                            // 18448 B
union K2Smem {
    NsSmem ns;
    float wl[64 * 64];                        // 16 KB
};
// K3: W2 bf16 hi/lo in B-fragment order + swizzled h tile + dis cache
struct K3Smem {
    unsigned w2f[16][64][4];   // slot = ct*4 + ks*2 + p (p: 0=hi,1=residual); 16 KB
    unsigned hbuf[16 * 32];    // bf16 h rows, XOR-swizzled 16B units; 2 KB
    float dis_s[16];
};                             // 18496 B

// ---------------------------------------------------------------------------
// binpack body: tile counting-sort into 391 bucket-strided regions (one
// global atomic per bucket per tile at implicit base b*CAPB).
// packed = (src<<8) | (dst & 255). 512 threads. src/dst read ONCE (kept in
// registers across phases; TILE = 8*512 guarantees 8 predicated iters).
// ---------------------------------------------------------------------------
__device__ __forceinline__ void binpack_body(const int* __restrict__ src,
                                             const int* __restrict__ dst, int E,
                                             int* __restrict__ cursor,
                                             unsigned* __restrict__ packed,
                                             int bid, BpSmem& sm) {
    int t  = threadIdx.x;
    int t0 = bid * TILE;
    int n  = min(TILE, E - t0);

    if (t < NBUCK) sm.hist[t] = 0;
    __syncthreads();
    int d_r[8], s_r[8];
#pragma unroll
    for (int it = 0; it < 8; ++it) {
        int i = t + it * 512;
        if (i < n) {
            d_r[it] = dst[t0 + i];
            s_r[it] = src[t0 + i];
            atomicAdd(&sm.hist[d_r[it] >> 8], 1);
        }
    }
    __syncthreads();
    int lane = t & 63, w = t >> 6;
    int v = (t < NBUCK) ? sm.hist[t] : 0;
    int s = v;
#pragma unroll
    for (int off = 1; off < 64; off <<= 1) {
        int u = __shfl_up(s, off, 64);
        if (lane >= off) s += u;
    }
    if (lane == 63) sm.wsum[w] = s;
    __syncthreads();
    if (t == 0) {
        int run = 0;
#pragma unroll
        for (int i = 0; i < 8; ++i) { int c = sm.wsum[i]; sm.wsum[i] = run; run += c; }
    }
    __syncthreads();
    if (t < NBUCK) {
        int ex = s - v + sm.wsum[w];
        sm.lofs[t] = ex;
        sm.lcur[t] = ex;
        sm.gbase[t] = t * CAPB + (v ? atomicAdd(&cursor[t], v) : 0);
    }
    __syncthreads();
#pragma unroll
    for (int it = 0; it < 8; ++it) {
        int i = t + it * 512;
        if (i < n) {
            int d = d_r[it];
            int b = d >> 8;
            int p = atomicAdd(&sm.lcur[b], 1);
            sm.stage[p] = ((unsigned)s_r[it] << 8) | (unsigned)(d & 255);
            sm.sbuck[p] = (unsigned short)b;
        }
    }
    __syncthreads();
    for (int i = t; i < n; i += 512) {
        int b = sm.sbuck[i];
        packed[sm.gbase[b] + (i - sm.lofs[b])] = sm.stage[i];
    }
}

// ---------------------------------------------------------------------------
// gemm body (f32 X): Ah = bf16(X @ W). VALU loop, x broadcast via readlane.
// 512 thr = 8 waves x 4 rows = 32 rows/block. Even lanes pack col pairs.
// ---------------------------------------------------------------------------
__device__ __forceinline__ void gemm_body(const float* __restrict__ X,
                                          const float* __restrict__ W,
                                          unsigned* __restrict__ Ah, int bid,
                                          float* wl) {
    int t = threadIdx.x;
    for (int i = t; i < 64 * 64; i += 512) wl[i] = W[i];
    __syncthreads();
    int lane = t & 63;
    int w    = t >> 6;
    float Wreg[64];
#pragma unroll
    for (int k = 0; k < 64; ++k) Wreg[k] = wl[k * 64 + lane];

    int row0 = bid * 32 + w * 4;
    const float* xp = X + (size_t)row0 * F;
    float xa = xp[lane];
    float xb = xp[64 + lane];
    float xc = xp[128 + lane];
    float xd = xp[192 + lane];
    float a0 = 0.f, a1 = 0.f, a2 = 0.f, a3 = 0.f;
#pragma unroll
    for (int k = 0; k < 64; ++k) {
        float wv = Wreg[k];
        a0 = fmaf(__uint_as_float(__builtin_amdgcn_readlane(__float_as_uint(xa), k)), wv, a0);
        a1 = fmaf(__uint_as_float(__builtin_amdgcn_readlane(__float_as_uint(xb), k)), wv, a1);
        a2 = fmaf(__uint_as_float(__builtin_amdgcn_readlane(__float_as_uint(xc), k)), wv, a2);
        a3 = fmaf(__uint_as_float(__builtin_amdgcn_readlane(__float_as_uint(xd), k)), wv, a3);
    }
    float p0 = __shfl_xor(a0, 1, 64);
    float p1 = __shfl_xor(a1, 1, 64);
    float p2 = __shfl_xor(a2, 1, 64);
    float p3 = __shfl_xor(a3, 1, 64);
    if (!(lane & 1)) {
        int c = lane >> 1;
        Ah[(size_t)(row0 + 0) * 32 + c] = pack2(a0, p0);
        Ah[(size_t)(row0 + 1) * 32 + c] = pack2(a1, p1);
        Ah[(size_t)(row0 + 2) * 32 + c] = pack2(a2, p2);
        Ah[(size_t)(row0 + 3) * 32 + c] = pack2(a3, p3);
    }
}

// ---------------------------------------------------------------------------
// node_sort body: per-bucket LDS counting sort to node order; emits row_ptr
// (absolute), deg, dis = rsqrt(deg+1). srt stays bucket-strided.
// packed read ONCE into registers (n <= CAPB = 8*512).
// ---------------------------------------------------------------------------
__device__ __forceinline__ void node_sort_body(const unsigned* __restrict__ packed,
                                               const int* __restrict__ cursor,
                                               int* __restrict__ row_ptr,
                                               int* __restrict__ deg,
                                               float* __restrict__ dis,
                                               int* __restrict__ srt,
                                               int b, NsSmem& sm) {
    int t = threadIdx.x;
    int nbase = b << 8;
    int nloc = min(256, NN - nbase);
    int beg = b * CAPB;
    int n = cursor[b];

    if (t < 256) sm.h[t] = 0;
    __syncthreads();
    unsigned p_r[8];
#pragma unroll
    for (int it = 0; it < 8; ++it) {
        int i = t + it * 512;
        if (i < n) {
            p_r[it] = packed[beg + i];
            atomicAdd(&sm.h[p_r[it] & 255u], 1);
        }
    }
    __syncthreads();
    int lane = t & 63, w = t >> 6;
    int v = 0, s = 0;
    if (t < 256) { v = sm.h[t]; s = v; }
#pragma unroll
    for (int off = 1; off < 64; off <<= 1) {
        int u = __shfl_up(s, off, 64);
        if (lane >= off) s += u;
    }
    if (t < 256 && lane == 63) sm.wsum[w] = s;
    __syncthreads();
    if (t == 0) {
        int run = 0;
#pragma unroll
        for (int i = 0; i < 4; ++i) { int c = sm.wsum[i]; sm.wsum[i] = run; run += c; }
    }
    __syncthreads();
    if (t < 256) {
        int e0 = s - v + sm.wsum[w];
        sm.lcur[t] = e0;
        if (t < nloc) {
            row_ptr[nbase + t] = beg + e0;
            deg[nbase + t]     = v;
            dis[nbase + t]     = rsqrtf((float)v + 1.0f);   // +1 = self-loop
        }
    }
    __syncthreads();
#pragma unroll
    for (int it = 0; it < 8; ++it) {
        int i = t + it * 512;
        if (i < n) {
            unsigned p = p_r[it];
            int pos = atomicAdd(&sm.lcur[p & 255u], 1);
            sm.stage[pos] = (int)(p >> 8);
        }
    }
    __syncthreads();
    for (int i = t; i < n; i += 512) srt[beg + i] = sm.stage[i];
}

// K1: binpack (blocks [0,nbp)) || layer-1 gemm part A (rest). LDS = union.
__global__ __launch_bounds__(512) void pre_gemm1(const int* __restrict__ src,
                                                 const int* __restrict__ dst, int E,
                                                 int nbp, int* __restrict__ cursor,
                                                 unsigned* __restrict__ packed,
                                                 const float* __restrict__ X,
                                                 const float* __restrict__ W1,
                                                 unsigned* __restrict__ Ah) {
    __shared__ KSmem sm;
    if ((int)blockIdx.x < nbp)
        binpack_body(src, dst, E, cursor, packed, blockIdx.x, sm.bp);
    else
        gemm_body(X, W1, Ah, (int)blockIdx.x - nbp, sm.wl);
}

// K2: node_sort (blocks [0,NBUCK)) || layer-1 gemm part B (rest).
__global__ __launch_bounds__(512) void sort_gemm1(const unsigned* __restrict__ packed,
                                                  const int* __restrict__ cursor,
                                                  int* __restrict__ row_ptr,
                                                  int* __restrict__ deg,
                                                  float* __restrict__ dis,
                                                  int* __restrict__ srt,
                                                  const float* __restrict__ X,
                                                  const float* __restrict__ W1,
                                                  unsigned* __restrict__ Ah) {
    __shared__ K2Smem sm;
    if ((int)blockIdx.x < NBUCK)
        node_sort_body(packed, cursor, row_ptr, deg, dis, srt, blockIdx.x, sm.ns);
    else
        gemm_body(X, W1, Ah, G1A + (int)blockIdx.x - NBUCK, sm.wl);
}

// ---------------------------------------------------------------------------
// K3: layer-1 aggregate fused with layer-2 transform (MFMA epilogue).
// Gather: 256 thr = 16 nodes x (2 edge-groups x 8 lanes), uint4 rows.
// Epilogue: h staged to swizzled LDS bf16 tile [16 nodes x 64]; W2 staged
// once per block as bf16 hi+residual in MFMA B-fragment order; each wave
// computes all 16 nodes x its 16-col tile via 4x mfma_f32_16x16x32_bf16
// (hi/lo split keeps W2 at ~f32 precision). Writes Bh = bf16(dis*(h@W2)).
// ---------------------------------------------------------------------------
__global__ __launch_bounds__(256) void agg1_gemm2(const uint4* __restrict__ Ah4,
                                                  const int* __restrict__ row_ptr,
                                                  const int* __restrict__ deg,
                                                  const int* __restrict__ srt,
                                                  const float* __restrict__ dis,
                                                  const float* __restrict__ b1,
                                                  const float* __restrict__ W2,
                                                  unsigned* __restrict__ Bh) {
    __shared__ K3Smem sm;
    int t = threadIdx.x;
    // stage W2 -> bf16 hi/residual fragments (B operand layout, per col-tile)
    for (int idx = t; idx < 4096; idx += 256) {
        int slot = idx >> 8;            // ct*4 + ks*2 + p
        int ks   = (slot >> 1) & 1;
        int p    = slot & 1;
        int ct   = slot >> 2;
        int l    = (idx >> 2) & 63;
        int j    = idx & 3;
        int k    = 32 * ks + 8 * (l >> 4) + 2 * j;
        int col  = 16 * ct + (l & 15);
        float v0 = W2[k * 64 + col];
        float v1 = W2[(k + 1) * 64 + col];
        if (p) {
            v0 -= __uint_as_float(bf_rne(v0) << 16);
            v1 -= __uint_as_float(bf_rne(v1) << 16);
        }
        sm.w2f[slot][l][j] = pack2(v0, v1);
    }

    int sub  = t & 7;            // col chunk: cols [8*sub, 8*sub+8)
    int grp  = (t >> 3) & 1;     // edge group
    int node = blockIdx.x * 16 + (t >> 4);
    int beg = row_ptr[node];
    int end = beg + deg[node];
    float di = dis[node];

    float a0, a1, a2, a3, a4, a5, a6, a7;
    uint4 su = Ah4[(size_t)node * 8 + sub];
    if (grp == 0) {
        a0 = di * lo_f(su.x); a1 = di * hi_f(su.x);
        a2 = di * lo_f(su.y); a3 = di * hi_f(su.y);
        a4 = di * lo_f(su.z); a5 = di * hi_f(su.z);
        a6 = di * lo_f(su.w); a7 = di * hi_f(su.w);
    } else {
        a0 = a1 = a2 = a3 = a4 = a5 = a6 = a7 = 0.f;
    }

    int j = beg + grp;
    for (; j + 6 < end; j += 8) {
        int s0 = srt[j], s1 = srt[j + 2], s2 = srt[j + 4], s3 = srt[j + 6];
        float d0 = dis[s0], d1 = dis[s1], d2 = dis[s2], d3 = dis[s3];
        uint4 g0 = Ah4[(size_t)s0 * 8 + sub];
        uint4 g1 = Ah4[(size_t)s1 * 8 + sub];
        uint4 g2 = Ah4[(size_t)s2 * 8 + sub];
        uint4 g3 = Ah4[(size_t)s3 * 8 + sub];
        a0 = fmaf(d0, lo_f(g0.x), fmaf(d1, lo_f(g1.x), fmaf(d2, lo_f(g2.x), fmaf(d3, lo_f(g3.x), a0))));
        a1 = fmaf(d0, hi_f(g0.x), fmaf(d1, hi_f(g1.x), fmaf(d2, hi_f(g2.x), fmaf(d3, hi_f(g3.x), a1))));
        a2 = fmaf(d0, lo_f(g0.y), fmaf(d1, lo_f(g1.y), fmaf(d2, lo_f(g2.y), fmaf(d3, lo_f(g3.y), a2))));
        a3 = fmaf(d0, hi_f(g0.y), fmaf(d1, hi_f(g1.y), fmaf(d2, hi_f(g2.y), fmaf(d3, hi_f(g3.y), a3))));
        a4 = fmaf(d0, lo_f(g0.z), fmaf(d1, lo_f(g1.z), fmaf(d2, lo_f(g2.z), fmaf(d3, lo_f(g3.z), a4))));
        a5 = fmaf(d0, hi_f(g0.z), fmaf(d1, hi_f(g1.z), fmaf(d2, hi_f(g2.z), fmaf(d3, hi_f(g3.z), a5))));
        a6 = fmaf(d0, lo_f(g0.w), fmaf(d1, lo_f(g1.w), fmaf(d2, lo_f(g2.w), fmaf(d3, lo_f(g3.w), a6))));
        a7 = fmaf(d0, hi_f(g0.w), fmaf(d1, hi_f(g1.w), fmaf(d2, hi_f(g2.w), fmaf(d3, hi_f(g3.w), a7))));
    }
    for (; j + 2 < end; j += 4) {
        int s0 = srt[j], s1 = srt[j + 2];
        float d0 = dis[s0], d1 = dis[s1];
        uint4 g0 = Ah4[(size_t)s0 * 8 + sub];
        uint4 g1 = Ah4[(size_t)s1 * 8 + sub];
        a0 = fmaf(d0, lo_f(g0.x), fmaf(d1, lo_f(g1.x), a0));
        a1 = fmaf(d0, hi_f(g0.x), fmaf(d1, hi_f(g1.x), a1));
        a2 = fmaf(d0, lo_f(g0.y), fmaf(d1, lo_f(g1.y), a2));
        a3 = fmaf(d0, hi_f(g0.y), fmaf(d1, hi_f(g1.y), a3));
        a4 = fmaf(d0, lo_f(g0.z), fmaf(d1, lo_f(g1.z), a4));
        a5 = fmaf(d0, hi_f(g0.z), fmaf(d1, hi_f(g1.z), a5));
        a6 = fmaf(d0, lo_f(g0.w), fmaf(d1, lo_f(g1.w), a6));
        a7 = fmaf(d0, hi_f(g0.w), fmaf(d1, hi_f(g1.w), a7));
    }
    for (; j < end; j += 2) {
        int s0 = srt[j];
        float d0 = dis[s0];
        uint4 g0 = Ah4[(size_t)s0 * 8 + sub];
        a0 = fmaf(d0, lo_f(g0.x), a0);
        a1 = fmaf(d0, hi_f(g0.x), a1);
        a2 = fmaf(d0, lo_f(g0.y), a2);
        a3 = fmaf(d0, hi_f(g0.y), a3);
        a4 = fmaf(d0, lo_f(g0.z), a4);
        a5 = fmaf(d0, hi_f(g0.z), a5);
        a6 = fmaf(d0, lo_f(g0.w), a6);
        a7 = fmaf(d0, hi_f(g0.w), a7);
    }
    // combine the two edge-groups (lane ^ 8 within each 16-lane node slice)
    a0 += __shfl_xor(a0, 8, 64); a1 += __shfl_xor(a1, 8, 64);
    a2 += __shfl_xor(a2, 8, 64); a3 += __shfl_xor(a3, 8, 64);
    a4 += __shfl_xor(a4, 8, 64); a5 += __shfl_xor(a5, 8, 64);
    a6 += __shfl_xor(a6, 8, 64); a7 += __shfl_xor(a7, 8, 64);

    float4 bb0 = ((const float4*)b1)[2 * sub];
    float4 bb1 = ((const float4*)b1)[2 * sub + 1];
    float o0 = fmaxf(fmaf(di, a0, bb0.x), 0.f);
    float o1 = fmaxf(fmaf(di, a1, bb0.y), 0.f);
    float o2 = fmaxf(fmaf(di, a2, bb0.z), 0.f);
    float o3 = fmaxf(fmaf(di, a3, bb0.w), 0.f);
    float o4 = fmaxf(fmaf(di, a4, bb1.x), 0.f);
    float o5 = fmaxf(fmaf(di, a5, bb1.y), 0.f);
    float o6 = fmaxf(fmaf(di, a6, bb1.z), 0.f);
    float o7 = fmaxf(fmaf(di, a7, bb1.w), 0.f);

    // stage h (bf16) into swizzled LDS tile; grp0 half writes
    int node15 = t >> 4;
    if (!(t & 8)) {
        int unit = sub ^ (node15 & 7);
        uint4 hv;
        hv.x = pack2(o0, o1);
        hv.y = pack2(o2, o3);
        hv.z = pack2(o4, o5);
        hv.w = pack2(o6, o7);
        *(uint4*)&sm.hbuf[node15 * 32 + unit * 4] = hv;
        if (sub == 0) sm.dis_s[node15] = di;
    }
    __syncthreads();

    // ---- MFMA h @ W2: wave ct covers cols [16ct,16ct+16), all 16 nodes ----
    int lane = t & 63, ct = t >> 6;
    int row = lane & 15, g = lane >> 4;
    f32x4 acc = {0.f, 0.f, 0.f, 0.f};
#pragma unroll
    for (int ks = 0; ks < 2; ++ks) {
        int unit = (4 * ks + g) ^ (row & 7);
        uint4 araw = *(const uint4*)&sm.hbuf[row * 32 + unit * 4];
        uint4 bhr  = *(const uint4*)&sm.w2f[ct * 4 + ks * 2 + 0][lane][0];
        uint4 blr  = *(const uint4*)&sm.w2f[ct * 4 + ks * 2 + 1][lane][0];
        bf16x8 A  = __builtin_bit_cast(bf16x8, araw);
        bf16x8 Bh_ = __builtin_bit_cast(bf16x8, bhr);
        bf16x8 Bl_ = __builtin_bit_cast(bf16x8, blr);
        acc = __builtin_amdgcn_mfma_f32_16x16x32_bf16(A, Bh_, acc, 0, 0, 0);
        acc = __builtin_amdgcn_mfma_f32_16x16x32_bf16(A, Bl_, acc, 0, 0, 0);
    }
    // C layout: col = lane&15, row(node) = 4*(lane>>4) + r
    int nbase16 = blockIdx.x * 16;
#pragma unroll
    for (int r = 0; r < 4; ++r) {
        int nd = 4 * g + r;
        float val = acc[r] * sm.dis_s[nd];
        float q = __shfl_xor(val, 1, 64);
        if (!(lane & 1)) {
            int colp = 8 * ct + ((lane & 15) >> 1);
            Bh[(size_t)(nbase16 + nd) * 32 + colp] = pack2(val, q);
        }
    }
}

// ---------------------------------------------------------------------------
// K4: layer-2 aggregate over pre-scaled bf16 Bh rows (no per-edge dis!),
// same 16-node x (2 grp x 8 lane) structure, f32 float4 output.
// ---------------------------------------------------------------------------
__global__ __launch_bounds__(256) void agg_out(const uint4* __restrict__ Bs4,
                                               const int* __restrict__ row_ptr,
                                               const int* __restrict__ deg,
                                               const int* __restrict__ srt,
                                               const float* __restrict__ dis,
                                               const float* __restrict__ bias,
                                               float* __restrict__ outp) {
    int t = threadIdx.x;
    int sub  = t & 7;
    int grp  = (t >> 3) & 1;
    int node = blockIdx.x * 16 + (t >> 4);
    int beg = row_ptr[node];
    int end = beg + deg[node];
    float di = dis[node];

    float a0, a1, a2, a3, a4, a5, a6, a7;
    uint4 su = Bs4[(size_t)node * 8 + sub];     // already dis-scaled
    if (grp == 0) {
        a0 = lo_f(su.x); a1 = hi_f(su.x);
        a2 = lo_f(su.y); a3 = hi_f(su.y);
        a4 = lo_f(su.z); a5 = hi_f(su.z);
        a6 = lo_f(su.w); a7 = hi_f(su.w);
    } else {
        a0 = a1 = a2 = a3 = a4 = a5 = a6 = a7 = 0.f;
    }

    int j = beg + grp;
    for (; j + 6 < end; j += 8) {
        int s0 = srt[j], s1 = srt[j + 2], s2 = srt[j + 4], s3 = srt[j + 6];
        uint4 g0 = Bs4[(size_t)s0 * 8 + sub];
        uint4 g1 = Bs4[(size_t)s1 * 8 + sub];
        uint4 g2 = Bs4[(size_t)s2 * 8 + sub];
        uint4 g3 = Bs4[(size_t)s3 * 8 + sub];
        a0 += (lo_f(g0.x) + lo_f(g1.x)) + (lo_f(g2.x) + lo_f(g3.x));
        a1 += (hi_f(g0.x) + hi_f(g1.x)) + (hi_f(g2.x) + hi_f(g3.x));
        a2 += (lo_f(g0.y) + lo_f(g1.y)) + (lo_f(g2.y) + lo_f(g3.y));
        a3 += (hi_f(g0.y) + hi_f(g1.y)) + (hi_f(g2.y) + hi_f(g3.y));
        a4 += (lo_f(g0.z) + lo_f(g1.z)) + (lo_f(g2.z) + lo_f(g3.z));
        a5 += (hi_f(g0.z) + hi_f(g1.z)) + (hi_f(g2.z) + hi_f(g3.z));
        a6 += (lo_f(g0.w) + lo_f(g1.w)) + (lo_f(g2.w) + lo_f(g3.w));
        a7 += (hi_f(g0.w) + hi_f(g1.w)) + (hi_f(g2.w) + hi_f(g3.w));
    }
    for (; j + 2 < end; j += 4) {
        int s0 = srt[j], s1 = srt[j + 2];
        uint4 g0 = Bs4[(size_t)s0 * 8 + sub];
        uint4 g1 = Bs4[(size_t)s1 * 8 + sub];
        a0 += lo_f(g0.x) + lo_f(g1.x);
        a1 += hi_f(g0.x) + hi_f(g1.x);
        a2 += lo_f(g0.y) + lo_f(g1.y);
        a3 += hi_f(g0.y) + hi_f(g1.y);
        a4 += lo_f(g0.z) + lo_f(g1.z);
        a5 += hi_f(g0.z) + hi_f(g1.z);
        a6 += lo_f(g0.w) + lo_f(g1.w);
        a7 += hi_f(g0.w) + hi_f(g1.w);
    }
    for (; j < end; j += 2) {
        int s0 = srt[j];
        uint4 g0 = Bs4[(size_t)s0 * 8 + sub];
        a0 += lo_f(g0.x); a1 += hi_f(g0.x);
        a2 += lo_f(g0.y); a3 += hi_f(g0.y);
        a4 += lo_f(g0.z); a5 += hi_f(g0.z);
        a6 += lo_f(g0.w); a7 += hi_f(g0.w);
    }
    a0 += __shfl_xor(a0, 8, 64); a1 += __shfl_xor(a1, 8, 64);
    a2 += __shfl_xor(a2, 8, 64); a3 += __shfl_xor(a3, 8, 64);
    a4 += __shfl_xor(a4, 8, 64); a5 += __shfl_xor(a5, 8, 64);
    a6 += __shfl_xor(a6, 8, 64); a7 += __shfl_xor(a7, 8, 64);

    float4 bb0 = ((const float4*)bias)[2 * sub];
    float4 bb1 = ((const float4*)bias)[2 * sub + 1];
    float4 o;
    if (grp == 0) {
        o.x = fmaf(di, a0, bb0.x);
        o.y = fmaf(di, a1, bb0.y);
        o.z = fmaf(di, a2, bb0.z);
        o.w = fmaf(di, a3, bb0.w);
        ((float4*)outp)[(size_t)node * 16 + 2 * sub] = o;
    } else {
        o.x = fmaf(di, a4, bb1.x);
        o.y = fmaf(di, a5, bb1.y);
        o.z = fmaf(di, a6, bb1.z);
        o.w = fmaf(di, a7, bb1.w);
        ((float4*)outp)[(size_t)node * 16 + 2 * sub + 1] = o;
    }
}

extern "C" void kernel_launch(void* const* d_in, const int* in_sizes, int n_in,
                              void* d_out, int out_size, void* d_ws, size_t ws_size,
                              hipStream_t stream) {
    const float* x  = (const float*)d_in[0];
    const int*   ei = (const int*)d_in[1];   // [2,E]: src = ei[0:E], dst = ei[E:2E]
    const float* W1 = (const float*)d_in[2];
    const float* b1 = (const float*)d_in[3];
    const float* W2 = (const float*)d_in[4];
    const float* b2 = (const float*)d_in[5];
    float* out = (float*)d_out;
    int E = in_sizes[1] / 2;
    const int* src = ei;
    const int* dst = ei + E;

    int*      ws_i    = (int*)d_ws;
    int*      cursor  = ws_i + O_CURSOR;
    int*      row_ptr = ws_i + O_ROWPTR;
    int*      deg     = ws_i + O_DEG;
    float*    dis     = (float*)(ws_i + O_DIS);
    unsigned* packed  = (unsigned*)(ws_i + O_PACKED);
    int*      srt     = ws_i + O_SRT;
    unsigned* Ah      = (unsigned*)(ws_i + O_AH);
    unsigned* Bh      = (unsigned*)(ws_i + O_BH);

    int nbp = (E + TILE - 1) / TILE;

    hipMemsetAsync(cursor, 0, NBUCK * sizeof(int), stream);
    // K1: binpack (first nbp blocks) || layer-1 gemm blocks [0, G1A)
    pre_gemm1<<<nbp + G1A, 512, 0, stream>>>(src, dst, E, nbp, cursor, packed,
                                             x, W1, Ah);
    // K2: node_sort (first NBUCK blocks) || layer-1 gemm blocks [G1A, G1TOT)
    sort_gemm1<<<NBUCK + (G1TOT - G1A), 512, 0, stream>>>(packed, cursor, row_ptr,
                                                          deg, dis, srt, x, W1, Ah);
    // K3: layer-1 aggregate + ReLU + fused layer-2 MFMA gemm -> bf16 Bh
    agg1_gemm2<<<NN / 16, 256, 0, stream>>>((const uint4*)Ah, row_ptr, deg, srt,
                                            dis, b1, W2, Bh);
    // K4: layer-2 aggregate -> f32 out
    agg_out<<<NN / 16, 256, 0, stream>>>((const uint4*)Bh, row_ptr, deg, srt,
                                         dis, b2, out);
}

// Round 4
// 187.767 us; speedup vs baseline: 1.0715x; 1.0715x over previous
//
#include <hip/hip_runtime.h>

#define NN    100000   // N_NODES
#define F     64       // feature dim (= hidden dim)
#define NBUCK 391      // ceil(NN/256) buckets of 256 nodes
#define CAPB  4096     // per-bucket edge capacity (mean 3197, 16-sigma margin)
#define TILE  4096     // edges per binpack tile
#define G1A   1600     // gemm1 blocks placed in K1 (rest overlap node_sort in K2)
#define G1TOT 3125     // NN/32 total gemm1 blocks

// workspace offsets (4-byte elements)
#define O_CURSOR 0          // int[391]
#define O_ROWPTR 512        // int[100000]  absolute index into srt
#define O_DEG    100864     // int[100000]
#define O_DIS    201216     // float[100000]
#define O_PACKED 301568     // uint[391*4096]
#define O_SRT    1903104    // int[391*4096 + 64]
#define O_AH     3504768    // uint[NN*32]: bf16-packed layer-1 A rows (128 B/row)
#define O_BH     6704768    // uint[NN*32]: bf16-packed layer-2 rows dis*(h@W2)
#define O_W2F    9904768    // uint[4096]: W2 bf16 hi/residual MFMA B-fragments

typedef __attribute__((ext_vector_type(8))) short bf16x8;
typedef __attribute__((ext_vector_type(4))) float f32x4;

// ---- bf16 pack/unpack (RNE; values finite) --------------------------------
__device__ __forceinline__ unsigned bf_rne(float x) {
    unsigned u = __float_as_uint(x);
    return (u + 0x7FFFu + ((u >> 16) & 1u)) >> 16;
}
__device__ __forceinline__ unsigned pack2(float lo, float hi) {
    return bf_rne(lo) | (bf_rne(hi) << 16);
}
__device__ __forceinline__ float lo_f(unsigned u) { return __uint_as_float(u << 16); }
__device__ __forceinline__ float hi_f(unsigned u) { return __uint_as_float(u & 0xFFFF0000u); }

// ---- shared-memory unions (per-block exclusive) ----------------------------
struct BpSmem {
    int hist[NBUCK], lofs[NBUCK], gbase[NBUCK], lcur[NBUCK];
    int wsum[8];
    unsigned stage[TILE];                     // 16 KB
    unsigned short sbuck[TILE];               // 8 KB
};                                            // 30864 B
union KSmem {
    BpSmem bp;
    float wl[64 * 64];                        // 16 KB
};
struct NsSmem {
    int h[256], lcur[256], wsum[4];
    int stage[CAPB];                          // 16 KB
};                                            // 18448 B
union K2Smem {
    NsSmem ns;
    float wl[64 * 64];                        // 16 KB
};
// K3: W2 bf16 hi/lo in B-fragment order + swizzled h tile + dis cache
struct K3Smem {
    unsigned w2f[16][64][4];   // slot = ct*4 + ks*2 + p (p: 0=hi,1=residual); 16 KB
    unsigned hbuf[16 * 32];    // bf16 h rows, XOR-swizzled 16B units; 2 KB
    float dis_s[16];
};                             // 18496 B

// ---------------------------------------------------------------------------
// binpack body: tile counting-sort into 391 bucket-strided regions (one
// global atomic per bucket per tile at implicit base b*CAPB).
// packed = (src<<8) | (dst & 255). 512 threads. src/dst read ONCE (kept in
// registers across phases; TILE = 8*512 guarantees 8 predicated iters).
// ---------------------------------------------------------------------------
__device__ __forceinline__ void binpack_body(const int* __restrict__ src,
                                             const int* __restrict__ dst, int E,
                                             int* __restrict__ cursor,
                                             unsigned* __restrict__ packed,
                                             int bid, BpSmem& sm) {
    int t  = threadIdx.x;
    int t0 = bid * TILE;
    int n  = min(TILE, E - t0);

    if (t < NBUCK) sm.hist[t] = 0;
    __syncthreads();
    int d_r[8], s_r[8];
#pragma unroll
    for (int it = 0; it < 8; ++it) {
        int i = t + it * 512;
        if (i < n) {
            d_r[it] = dst[t0 + i];
            s_r[it] = src[t0 + i];
            atomicAdd(&sm.hist[d_r[it] >> 8], 1);
        }
    }
    __syncthreads();
    int lane = t & 63, w = t >> 6;
    int v = (t < NBUCK) ? sm.hist[t] : 0;
    int s = v;
#pragma unroll
    for (int off = 1; off < 64; off <<= 1) {
        int u = __shfl_up(s, off, 64);
        if (lane >= off) s += u;
    }
    if (lane == 63) sm.wsum[w] = s;
    __syncthreads();
    if (t == 0) {
        int run = 0;
#pragma unroll
        for (int i = 0; i < 8; ++i) { int c = sm.wsum[i]; sm.wsum[i] = run; run += c; }
    }
    __syncthreads();
    if (t < NBUCK) {
        int ex = s - v + sm.wsum[w];
        sm.lofs[t] = ex;
        sm.lcur[t] = ex;
        sm.gbase[t] = t * CAPB + (v ? atomicAdd(&cursor[t], v) : 0);
    }
    __syncthreads();
#pragma unroll
    for (int it = 0; it < 8; ++it) {
        int i = t + it * 512;
        if (i < n) {
            int d = d_r[it];
            int b = d >> 8;
            int p = atomicAdd(&sm.lcur[b], 1);
            sm.stage[p] = ((unsigned)s_r[it] << 8) | (unsigned)(d & 255);
            sm.sbuck[p] = (unsigned short)b;
        }
    }
    __syncthreads();
    for (int i = t; i < n; i += 512) {
        int b = sm.sbuck[i];
        packed[sm.gbase[b] + (i - sm.lofs[b])] = sm.stage[i];
    }
}

// ---------------------------------------------------------------------------
// gemm body (f32 X): Ah = bf16(X @ W). VALU loop, x broadcast via readlane.
// 512 thr = 8 waves x 4 rows = 32 rows/block. Even lanes pack col pairs.
// ---------------------------------------------------------------------------
__device__ __forceinline__ void gemm_body(const float* __restrict__ X,
                                          const float* __restrict__ W,
                                          unsigned* __restrict__ Ah, int bid,
                                          float* wl) {
    int t = threadIdx.x;
    for (int i = t; i < 64 * 64; i += 512) wl[i] = W[i];
    __syncthreads();
    int lane = t & 63;
    int w    = t >> 6;
    float Wreg[64];
#pragma unroll
    for (int k = 0; k < 64; ++k) Wreg[k] = wl[k * 64 + lane];

    int row0 = bid * 32 + w * 4;
    const float* xp = X + (size_t)row0 * F;
    float xa = xp[lane];
    float xb = xp[64 + lane];
    float xc = xp[128 + lane];
    float xd = xp[192 + lane];
    float a0 = 0.f, a1 = 0.f, a2 = 0.f, a3 = 0.f;
#pragma unroll
    for (int k = 0; k < 64; ++k) {
        float wv = Wreg[k];
        a0 = fmaf(__uint_as_float(__builtin_amdgcn_readlane(__float_as_uint(xa), k)), wv, a0);
        a1 = fmaf(__uint_as_float(__builtin_amdgcn_readlane(__float_as_uint(xb), k)), wv, a1);
        a2 = fmaf(__uint_as_float(__builtin_amdgcn_readlane(__float_as_uint(xc), k)), wv, a2);
        a3 = fmaf(__uint_as_float(__builtin_amdgcn_readlane(__float_as_uint(xd), k)), wv, a3);
    }
    float p0 = __shfl_xor(a0, 1, 64);
    float p1 = __shfl_xor(a1, 1, 64);
    float p2 = __shfl_xor(a2, 1, 64);
    float p3 = __shfl_xor(a3, 1, 64);
    if (!(lane & 1)) {
        int c = lane >> 1;
        Ah[(size_t)(row0 + 0) * 32 + c] = pack2(a0, p0);
        Ah[(size_t)(row0 + 1) * 32 + c] = pack2(a1, p1);
        Ah[(size_t)(row0 + 2) * 32 + c] = pack2(a2, p2);
        Ah[(size_t)(row0 + 3) * 32 + c] = pack2(a3, p3);
    }
}

// ---------------------------------------------------------------------------
// W2 fragment precompute (runs once, as one extra block of K1): emits the
// MFMA B-operand layout, bf16 hi (p=0) + bf16 residual (p=1), linear words.
// word idx: slot = idx>>8 (= ct*4 + ks*2 + p), l = (idx>>2)&63, j = idx&3.
// ---------------------------------------------------------------------------
__device__ __forceinline__ void w2prep_body(const float* __restrict__ W2,
                                            unsigned* __restrict__ w2f) {
    int t = threadIdx.x;
    for (int idx = t; idx < 4096; idx += 512) {
        int slot = idx >> 8;
        int ks   = (slot >> 1) & 1;
        int p    = slot & 1;
        int ct   = slot >> 2;
        int l    = (idx >> 2) & 63;
        int j    = idx & 3;
        int k    = 32 * ks + 8 * (l >> 4) + 2 * j;
        int col  = 16 * ct + (l & 15);
        float v0 = W2[k * 64 + col];
        float v1 = W2[(k + 1) * 64 + col];
        if (p) {
            v0 -= __uint_as_float(bf_rne(v0) << 16);
            v1 -= __uint_as_float(bf_rne(v1) << 16);
        }
        w2f[idx] = pack2(v0, v1);
    }
}

// ---------------------------------------------------------------------------
// node_sort body: per-bucket LDS counting sort to node order; emits row_ptr
// (absolute), deg, dis = rsqrt(deg+1). srt stays bucket-strided.
// packed read ONCE into registers (n <= CAPB = 8*512).
// ---------------------------------------------------------------------------
__device__ __forceinline__ void node_sort_body(const unsigned* __restrict__ packed,
                                               const int* __restrict__ cursor,
                                               int* __restrict__ row_ptr,
                                               int* __restrict__ deg,
                                               float* __restrict__ dis,
                                               int* __restrict__ srt,
                                               int b, NsSmem& sm) {
    int t = threadIdx.x;
    int nbase = b << 8;
    int nloc = min(256, NN - nbase);
    int beg = b * CAPB;
    int n = cursor[b];

    if (t < 256) sm.h[t] = 0;
    __syncthreads();
    unsigned p_r[8];
#pragma unroll
    for (int it = 0; it < 8; ++it) {
        int i = t + it * 512;
        if (i < n) {
            p_r[it] = packed[beg + i];
            atomicAdd(&sm.h[p_r[it] & 255u], 1);
        }
    }
    __syncthreads();
    int lane = t & 63, w = t >> 6;
    int v = 0, s = 0;
    if (t < 256) { v = sm.h[t]; s = v; }
#pragma unroll
    for (int off = 1; off < 64; off <<= 1) {
        int u = __shfl_up(s, off, 64);
        if (lane >= off) s += u;
    }
    if (t < 256 && lane == 63) sm.wsum[w] = s;
    __syncthreads();
    if (t == 0) {
        int run = 0;
#pragma unroll
        for (int i = 0; i < 4; ++i) { int c = sm.wsum[i]; sm.wsum[i] = run; run += c; }
    }
    __syncthreads();
    if (t < 256) {
        int e0 = s - v + sm.wsum[w];
        sm.lcur[t] = e0;
        if (t < nloc) {
            row_ptr[nbase + t] = beg + e0;
            deg[nbase + t]     = v;
            dis[nbase + t]     = rsqrtf((float)v + 1.0f);   // +1 = self-loop
        }
    }
    __syncthreads();
#pragma unroll
    for (int it = 0; it < 8; ++it) {
        int i = t + it * 512;
        if (i < n) {
            unsigned p = p_r[it];
            int pos = atomicAdd(&sm.lcur[p & 255u], 1);
            sm.stage[pos] = (int)(p >> 8);
        }
    }
    __syncthreads();
    for (int i = t; i < n; i += 512) srt[beg + i] = sm.stage[i];
}

// K1: binpack (blocks [0,nbp)) || layer-1 gemm part A || W2 fragment prep.
__global__ __launch_bounds__(512) void pre_gemm1(const int* __restrict__ src,
                                                 const int* __restrict__ dst, int E,
                                                 int nbp, int* __restrict__ cursor,
                                                 unsigned* __restrict__ packed,
                                                 const float* __restrict__ X,
                                                 const float* __restrict__ W1,
                                                 unsigned* __restrict__ Ah,
                                                 const float* __restrict__ W2,
                                                 unsigned* __restrict__ w2f) {
    __shared__ KSmem sm;
    if ((int)blockIdx.x < nbp)
        binpack_body(src, dst, E, cursor, packed, blockIdx.x, sm.bp);
    else if ((int)blockIdx.x < nbp + G1A)
        gemm_body(X, W1, Ah, (int)blockIdx.x - nbp, sm.wl);
    else
        w2prep_body(W2, w2f);
}

// K2: node_sort (blocks [0,NBUCK)) || layer-1 gemm part B (rest).
__global__ __launch_bounds__(512) void sort_gemm1(const unsigned* __restrict__ packed,
                                                  const int* __restrict__ cursor,
                                                  int* __restrict__ row_ptr,
                                                  int* __restrict__ deg,
                                                  float* __restrict__ dis,
                                                  int* __restrict__ srt,
                                                  const float* __restrict__ X,
                                                  const float* __restrict__ W1,
                                                  unsigned* __restrict__ Ah) {
    __shared__ K2Smem sm;
    if ((int)blockIdx.x < NBUCK)
        node_sort_body(packed, cursor, row_ptr, deg, dis, srt, blockIdx.x, sm.ns);
    else
        gemm_body(X, W1, Ah, G1A + (int)blockIdx.x - NBUCK, sm.wl);
}

// ---------------------------------------------------------------------------
// K3: layer-1 aggregate fused with layer-2 transform (MFMA epilogue).
// Gather: 256 thr = 16 nodes x (2 edge-groups x 8 lanes), uint4 rows.
// W2 fragments loaded from precomputed workspace (4 coalesced uint4/thread).
// Epilogue: h staged to swizzled LDS bf16 tile [16 nodes x 64]; each wave
// computes all 16 nodes x its 16-col tile via 4x mfma_f32_16x16x32_bf16
// (hi/residual split keeps W2 at ~f32 precision). Writes Bh = bf16(dis*(h@W2)).
// ---------------------------------------------------------------------------
__global__ __launch_bounds__(256) void agg1_gemm2(const uint4* __restrict__ Ah4,
                                                  const int* __restrict__ row_ptr,
                                                  const int* __restrict__ deg,
                                                  const int* __restrict__ srt,
                                                  const float* __restrict__ dis,
                                                  const float* __restrict__ b1,
                                                  const unsigned* __restrict__ w2fg,
                                                  unsigned* __restrict__ Bh) {
    __shared__ K3Smem sm;
    int t = threadIdx.x;
    // stage precomputed W2 fragments: 1024 uint4, coalesced, L2-resident
#pragma unroll
    for (int i = 0; i < 4; ++i)
        ((uint4*)sm.w2f)[t + 256 * i] = ((const uint4*)w2fg)[t + 256 * i];

    int sub  = t & 7;            // col chunk: cols [8*sub, 8*sub+8)
    int grp  = (t >> 3) & 1;     // edge group
    int node = blockIdx.x * 16 + (t >> 4);
    int beg = row_ptr[node];
    int end = beg + deg[node];
    float di = dis[node];

    float a0, a1, a2, a3, a4, a5, a6, a7;
    uint4 su = Ah4[(size_t)node * 8 + sub];
    if (grp == 0) {
        a0 = di * lo_f(su.x); a1 = di * hi_f(su.x);
        a2 = di * lo_f(su.y); a3 = di * hi_f(su.y);
        a4 = di * lo_f(su.z); a5 = di * hi_f(su.z);
        a6 = di * lo_f(su.w); a7 = di * hi_f(su.w);
    } else {
        a0 = a1 = a2 = a3 = a4 = a5 = a6 = a7 = 0.f;
    }

    int j = beg + grp;
    for (; j + 6 < end; j += 8) {
        int s0 = srt[j], s1 = srt[j + 2], s2 = srt[j + 4], s3 = srt[j + 6];
        float d0 = dis[s0], d1 = dis[s1], d2 = dis[s2], d3 = dis[s3];
        uint4 g0 = Ah4[(size_t)s0 * 8 + sub];
        uint4 g1 = Ah4[(size_t)s1 * 8 + sub];
        uint4 g2 = Ah4[(size_t)s2 * 8 + sub];
        uint4 g3 = Ah4[(size_t)s3 * 8 + sub];
        a0 = fmaf(d0, lo_f(g0.x), fmaf(d1, lo_f(g1.x), fmaf(d2, lo_f(g2.x), fmaf(d3, lo_f(g3.x), a0))));
        a1 = fmaf(d0, hi_f(g0.x), fmaf(d1, hi_f(g1.x), fmaf(d2, hi_f(g2.x), fmaf(d3, hi_f(g3.x), a1))));
        a2 = fmaf(d0, lo_f(g0.y), fmaf(d1, lo_f(g1.y), fmaf(d2, lo_f(g2.y), fmaf(d3, lo_f(g3.y), a2))));
        a3 = fmaf(d0, hi_f(g0.y), fmaf(d1, hi_f(g1.y), fmaf(d2, hi_f(g2.y), fmaf(d3, hi_f(g3.y), a3))));
        a4 = fmaf(d0, lo_f(g0.z), fmaf(d1, lo_f(g1.z), fmaf(d2, lo_f(g2.z), fmaf(d3, lo_f(g3.z), a4))));
        a5 = fmaf(d0, hi_f(g0.z), fmaf(d1, hi_f(g1.z), fmaf(d2, hi_f(g2.z), fmaf(d3, hi_f(g3.z), a5))));
        a6 = fmaf(d0, lo_f(g0.w), fmaf(d1, lo_f(g1.w), fmaf(d2, lo_f(g2.w), fmaf(d3, lo_f(g3.w), a6))));
        a7 = fmaf(d0, hi_f(g0.w), fmaf(d1, hi_f(g1.w), fmaf(d2, hi_f(g2.w), fmaf(d3, hi_f(g3.w), a7))));
    }
    for (; j + 2 < end; j += 4) {
        int s0 = srt[j], s1 = srt[j + 2];
        float d0 = dis[s0], d1 = dis[s1];
        uint4 g0 = Ah4[(size_t)s0 * 8 + sub];
        uint4 g1 = Ah4[(size_t)s1 * 8 + sub];
        a0 = fmaf(d0, lo_f(g0.x), fmaf(d1, lo_f(g1.x), a0));
        a1 = fmaf(d0, hi_f(g0.x), fmaf(d1, hi_f(g1.x), a1));
        a2 = fmaf(d0, lo_f(g0.y), fmaf(d1, lo_f(g1.y), a2));
        a3 = fmaf(d0, hi_f(g0.y), fmaf(d1, hi_f(g1.y), a3));
        a4 = fmaf(d0, lo_f(g0.z), fmaf(d1, lo_f(g1.z), a4));
        a5 = fmaf(d0, hi_f(g0.z), fmaf(d1, hi_f(g1.z), a5));
        a6 = fmaf(d0, lo_f(g0.w), fmaf(d1, lo_f(g1.w), a6));
        a7 = fmaf(d0, hi_f(g0.w), fmaf(d1, hi_f(g1.w), a7));
    }
    for (; j < end; j += 2) {
        int s0 = srt[j];
        float d0 = dis[s0];
        uint4 g0 = Ah4[(size_t)s0 * 8 + sub];
        a0 = fmaf(d0, lo_f(g0.x), a0);
        a1 = fmaf(d0, hi_f(g0.x), a1);
        a2 = fmaf(d0, lo_f(g0.y), a2);
        a3 = fmaf(d0, hi_f(g0.y), a3);
        a4 = fmaf(d0, lo_f(g0.z), a4);
        a5 = fmaf(d0, hi_f(g0.z), a5);
        a6 = fmaf(d0, lo_f(g0.w), a6);
        a7 = fmaf(d0, hi_f(g0.w), a7);
    }
    // combine the two edge-groups (lane ^ 8 within each 16-lane node slice)
    a0 += __shfl_xor(a0, 8, 64); a1 += __shfl_xor(a1, 8, 64);
    a2 += __shfl_xor(a2, 8, 64); a3 += __shfl_xor(a3, 8, 64);
    a4 += __shfl_xor(a4, 8, 64); a5 += __shfl_xor(a5, 8, 64);
    a6 += __shfl_xor(a6, 8, 64); a7 += __shfl_xor(a7, 8, 64);

    float4 bb0 = ((const float4*)b1)[2 * sub];
    float4 bb1 = ((const float4*)b1)[2 * sub + 1];
    float o0 = fmaxf(fmaf(di, a0, bb0.x), 0.f);
    float o1 = fmaxf(fmaf(di, a1, bb0.y), 0.f);
    float o2 = fmaxf(fmaf(di, a2, bb0.z), 0.f);
    float o3 = fmaxf(fmaf(di, a3, bb0.w), 0.f);
    float o4 = fmaxf(fmaf(di, a4, bb1.x), 0.f);
    float o5 = fmaxf(fmaf(di, a5, bb1.y), 0.f);
    float o6 = fmaxf(fmaf(di, a6, bb1.z), 0.f);
    float o7 = fmaxf(fmaf(di, a7, bb1.w), 0.f);

    // stage h (bf16) into swizzled LDS tile; grp0 half writes
    int node15 = t >> 4;
    if (!(t & 8)) {
        int unit = sub ^ (node15 & 7);
        uint4 hv;
        hv.x = pack2(o0, o1);
        hv.y = pack2(o2, o3);
        hv.z = pack2(o4, o5);
        hv.w = pack2(o6, o7);
        *(uint4*)&sm.hbuf[node15 * 32 + unit * 4] = hv;
        if (sub == 0) sm.dis_s[node15] = di;
    }
    __syncthreads();

    // ---- MFMA h @ W2: wave ct covers cols [16ct,16ct+16), all 16 nodes ----
    int lane = t & 63, ct = t >> 6;
    int row = lane & 15, g = lane >> 4;
    f32x4 acc = {0.f, 0.f, 0.f, 0.f};
#pragma unroll
    for (int ks = 0; ks < 2; ++ks) {
        int unit = (4 * ks + g) ^ (row & 7);
        uint4 araw = *(const uint4*)&sm.hbuf[row * 32 + unit * 4];
        uint4 bhr  = *(const uint4*)&sm.w2f[ct * 4 + ks * 2 + 0][lane][0];
        uint4 blr  = *(const uint4*)&sm.w2f[ct * 4 + ks * 2 + 1][lane][0];
        bf16x8 A  = __builtin_bit_cast(bf16x8, araw);
        bf16x8 Bh_ = __builtin_bit_cast(bf16x8, bhr);
        bf16x8 Bl_ = __builtin_bit_cast(bf16x8, blr);
        acc = __builtin_amdgcn_mfma_f32_16x16x32_bf16(A, Bh_, acc, 0, 0, 0);
        acc = __builtin_amdgcn_mfma_f32_16x16x32_bf16(A, Bl_, acc, 0, 0, 0);
    }
    // C layout: col = lane&15, row(node) = 4*(lane>>4) + r
    int nbase16 = blockIdx.x * 16;
#pragma unroll
    for (int r = 0; r < 4; ++r) {
        int nd = 4 * g + r;
        float val = acc[r] * sm.dis_s[nd];
        float q = __shfl_xor(val, 1, 64);
        if (!(lane & 1)) {
            int colp = 8 * ct + ((lane & 15) >> 1);
            Bh[(size_t)(nbase16 + nd) * 32 + colp] = pack2(val, q);
        }
    }
}

// ---------------------------------------------------------------------------
// K4: layer-2 aggregate over pre-scaled bf16 Bh rows (no per-edge dis!),
// same 16-node x (2 grp x 8 lane) structure, f32 float4 output.
// ---------------------------------------------------------------------------
__global__ __launch_bounds__(256) void agg_out(const uint4* __restrict__ Bs4,
                                               const int* __restrict__ row_ptr,
                                               const int* __restrict__ deg,
                                               const int* __restrict__ srt,
                                               const float* __restrict__ dis,
                                               const float* __restrict__ bias,
                                               float* __restrict__ outp) {
    int t = threadIdx.x;
    int sub  = t & 7;
    int grp  = (t >> 3) & 1;
    int node = blockIdx.x * 16 + (t >> 4);
    int beg = row_ptr[node];
    int end = beg + deg[node];
    float di = dis[node];

    float a0, a1, a2, a3, a4, a5, a6, a7;
    uint4 su = Bs4[(size_t)node * 8 + sub];     // already dis-scaled
    if (grp == 0) {
        a0 = lo_f(su.x); a1 = hi_f(su.x);
        a2 = lo_f(su.y); a3 = hi_f(su.y);
        a4 = lo_f(su.z); a5 = hi_f(su.z);
        a6 = lo_f(su.w); a7 = hi_f(su.w);
    } else {
        a0 = a1 = a2 = a3 = a4 = a5 = a6 = a7 = 0.f;
    }

    int j = beg + grp;
    for (; j + 6 < end; j += 8) {
        int s0 = srt[j], s1 = srt[j + 2], s2 = srt[j + 4], s3 = srt[j + 6];
        uint4 g0 = Bs4[(size_t)s0 * 8 + sub];
        uint4 g1 = Bs4[(size_t)s1 * 8 + sub];
        uint4 g2 = Bs4[(size_t)s2 * 8 + sub];
        uint4 g3 = Bs4[(size_t)s3 * 8 + sub];
        a0 += (lo_f(g0.x) + lo_f(g1.x)) + (lo_f(g2.x) + lo_f(g3.x));
        a1 += (hi_f(g0.x) + hi_f(g1.x)) + (hi_f(g2.x) + hi_f(g3.x));
        a2 += (lo_f(g0.y) + lo_f(g1.y)) + (lo_f(g2.y) + lo_f(g3.y));
        a3 += (hi_f(g0.y) + hi_f(g1.y)) + (hi_f(g2.y) + hi_f(g3.y));
        a4 += (lo_f(g0.z) + lo_f(g1.z)) + (lo_f(g2.z) + lo_f(g3.z));
        a5 += (hi_f(g0.z) + hi_f(g1.z)) + (hi_f(g2.z) + hi_f(g3.z));
        a6 += (lo_f(g0.w) + lo_f(g1.w)) + (lo_f(g2.w) + lo_f(g3.w));
        a7 += (hi_f(g0.w) + hi_f(g1.w)) + (hi_f(g2.w) + hi_f(g3.w));
    }
    for (; j + 2 < end; j += 4) {
        int s0 = srt[j], s1 = srt[j + 2];
        uint4 g0 = Bs4[(size_t)s0 * 8 + sub];
        uint4 g1 = Bs4[(size_t)s1 * 8 + sub];
        a0 += lo_f(g0.x) + lo_f(g1.x);
        a1 += hi_f(g0.x) + hi_f(g1.x);
        a2 += lo_f(g0.y) + lo_f(g1.y);
        a3 += hi_f(g0.y) + hi_f(g1.y);
        a4 += lo_f(g0.z) + lo_f(g1.z);
        a5 += hi_f(g0.z) + hi_f(g1.z);
        a6 += lo_f(g0.w) + lo_f(g1.w);
        a7 += hi_f(g0.w) + hi_f(g1.w);
    }
    for (; j < end; j += 2) {
        int s0 = srt[j];
        uint4 g0 = Bs4[(size_t)s0 * 8 + sub];
        a0 += lo_f(g0.x); a1 += hi_f(g0.x);
        a2 += lo_f(g0.y); a3 += hi_f(g0.y);
        a4 += lo_f(g0.z); a5 += hi_f(g0.z);
        a6 += lo_f(g0.w); a7 += hi_f(g0.w);
    }
    a0 += __shfl_xor(a0, 8, 64); a1 += __shfl_xor(a1, 8, 64);
    a2 += __shfl_xor(a2, 8, 64); a3 += __shfl_xor(a3, 8, 64);
    a4 += __shfl_xor(a4, 8, 64); a5 += __shfl_xor(a5, 8, 64);
    a6 += __shfl_xor(a6, 8, 64); a7 += __shfl_xor(a7, 8, 64);

    float4 bb0 = ((const float4*)bias)[2 * sub];
    float4 bb1 = ((const float4*)bias)[2 * sub + 1];
    float4 o;
    if (grp == 0) {
        o.x = fmaf(di, a0, bb0.x);
        o.y = fmaf(di, a1, bb0.y);
        o.z = fmaf(di, a2, bb0.z);
        o.w = fmaf(di, a3, bb0.w);
        ((float4*)outp)[(size_t)node * 16 + 2 * sub] = o;
    } else {
        o.x = fmaf(di, a4, bb1.x);
        o.y = fmaf(di, a5, bb1.y);
        o.z = fmaf(di, a6, bb1.z);
        o.w = fmaf(di, a7, bb1.w);
        ((float4*)outp)[(size_t)node * 16 + 2 * sub + 1] = o;
    }
}

extern "C" void kernel_launch(void* const* d_in, const int* in_sizes, int n_in,
                              void* d_out, int out_size, void* d_ws, size_t ws_size,
                              hipStream_t stream) {
    const float* x  = (const float*)d_in[0];
    const int*   ei = (const int*)d_in[1];   // [2,E]: src = ei[0:E], dst = ei[E:2E]
    const float* W1 = (const float*)d_in[2];
    const float* b1 = (const float*)d_in[3];
    const float* W2 = (const float*)d_in[4];
    const float* b2 = (const float*)d_in[5];
    float* out = (float*)d_out;
    int E = in_sizes[1] / 2;
    const int* src = ei;
    const int* dst = ei + E;

    int*      ws_i    = (int*)d_ws;
    int*      cursor  = ws_i + O_CURSOR;
    int*      row_ptr = ws_i + O_ROWPTR;
    int*      deg     = ws_i + O_DEG;
    float*    dis     = (float*)(ws_i + O_DIS);
    unsigned* packed  = (unsigned*)(ws_i + O_PACKED);
    int*      srt     = ws_i + O_SRT;
    unsigned* Ah      = (unsigned*)(ws_i + O_AH);
    unsigned* Bh      = (unsigned*)(ws_i + O_BH);
    unsigned* w2f     = (unsigned*)(ws_i + O_W2F);

    int nbp = (E + TILE - 1) / TILE;

    hipMemsetAsync(cursor, 0, NBUCK * sizeof(int), stream);
    // K1: binpack (first nbp blocks) || layer-1 gemm blocks [0, G1A) || W2 prep
    pre_gemm1<<<nbp + G1A + 1, 512, 0, stream>>>(src, dst, E, nbp, cursor, packed,
                                                 x, W1, Ah, W2, w2f);
    // K2: node_sort (first NBUCK blocks) || layer-1 gemm blocks [G1A, G1TOT)
    sort_gemm1<<<NBUCK + (G1TOT - G1A), 512, 0, stream>>>(packed, cursor, row_ptr,
                                                          deg, dis, srt, x, W1, Ah);
    // K3: layer-1 aggregate + ReLU + fused layer-2 MFMA gemm -> bf16 Bh
    agg1_gemm2<<<NN / 16, 256, 0, stream>>>((const uint4*)Ah, row_ptr, deg, srt,
                                            dis, b1, w2f, Bh);
    // K4: layer-2 aggregate -> f32 out
    agg_out<<<NN / 16, 256, 0, stream>>>((const uint4*)Bh, row_ptr, deg, srt,
                                         dis, b2, out);
}

// Round 6
// 182.719 us; speedup vs baseline: 1.1011x; 1.0276x over previous
//
#include <hip/hip_runtime.h>

#define NN    100000   // N_NODES
#define F     64       // feature dim (= hidden dim)
#define NBUCK 391      // ceil(NN/256) buckets of 256 nodes
#define CAPB  4096     // per-bucket edge capacity (mean 3197, 16-sigma margin)
#define TILE  4096     // edges per binpack tile
#define NBLKG 782      // ceil(NN/128) MFMA gemm1 blocks (128 rows each)
#define G1A   400      // gemm1 blocks placed in K1 (rest overlap node_sort in K2)

// workspace offsets (4-byte elements)
#define O_CURSOR 0          // int[391]
#define O_ROWPTR 512        // int[100000]  absolute index into srt
#define O_DEG    100864     // int[100000]
#define O_DIS    201216     // float[100000]
#define O_PACKED 301568     // uint[391*4096]
#define O_SRT    1903104    // int[391*4096 + 64]
#define O_AH     3504768    // uint[NN*32]: bf16-packed layer-1 A rows (128 B/row)
#define O_BH     6704768    // uint[NN*32]: bf16-packed layer-2 rows dis*(h@W2)
#define O_W2F    9904768    // uint[4096]: W2 bf16 hi/residual MFMA B-fragments

typedef __attribute__((ext_vector_type(8))) short bf16x8;
typedef __attribute__((ext_vector_type(4))) float f32x4;

// ---- bf16 pack/unpack (RNE; values finite) --------------------------------
__device__ __forceinline__ unsigned bf_rne(float x) {
    unsigned u = __float_as_uint(x);
    return (u + 0x7FFFu + ((u >> 16) & 1u)) >> 16;
}
__device__ __forceinline__ unsigned pack2(float lo, float hi) {
    return bf_rne(lo) | (bf_rne(hi) << 16);
}
__device__ __forceinline__ float lo_f(unsigned u) { return __uint_as_float(u << 16); }
__device__ __forceinline__ float hi_f(unsigned u) { return __uint_as_float(u & 0xFFFF0000u); }

// ---- shared-memory unions (per-block exclusive) ----------------------------
struct BpSmem {
    int hist[NBUCK], lofs[NBUCK], gbase[NBUCK], lcur[NBUCK];
    int wsum[8];
    unsigned stage[TILE];                     // 16 KB
    unsigned short sbuck[TILE];               // 8 KB
};                                            // 30864 B
union KSmem {
    BpSmem bp;
    unsigned w1f[16][64][4];                  // 16 KB MFMA B-fragments of W1
};
struct NsSmem {
    int h[256], lcur[256], wsum[4];
    int stage[CAPB];                          // 16 KB
};                                            // 18448 B
union K2Smem {
    NsSmem ns;
    unsigned w1f[16][64][4];                  // 16 KB
};
// K3: W2 bf16 hi/lo in B-fragment order + swizzled h tile + dis cache
struct K3Smem {
    unsigned w2f[16][64][4];   // slot = ct*4 + ks*2 + p (p: 0=hi,1=residual); 16 KB
    unsigned hbuf[16 * 32];    // bf16 h rows, XOR-swizzled 16B units; 2 KB
    float dis_s[16];
};                             // 18496 B

// ---------------------------------------------------------------------------
// binpack body: tile counting-sort into 391 bucket-strided regions (one
// global atomic per bucket per tile at implicit base b*CAPB).
// packed = (src<<8) | (dst & 255). 512 threads. src/dst read ONCE (kept in
// registers across phases; TILE = 8*512 guarantees 8 predicated iters).
// ---------------------------------------------------------------------------
__device__ __forceinline__ void binpack_body(const int* __restrict__ src,
                                             const int* __restrict__ dst, int E,
                                             int* __restrict__ cursor,
                                             unsigned* __restrict__ packed,
                                             int bid, BpSmem& sm) {
    int t  = threadIdx.x;
    int t0 = bid * TILE;
    int n  = min(TILE, E - t0);

    if (t < NBUCK) sm.hist[t] = 0;
    __syncthreads();
    int d_r[8], s_r[8];
#pragma unroll
    for (int it = 0; it < 8; ++it) {
        int i = t + it * 512;
        if (i < n) {
            d_r[it] = dst[t0 + i];
            s_r[it] = src[t0 + i];
            atomicAdd(&sm.hist[d_r[it] >> 8], 1);
        }
    }
    __syncthreads();
    int lane = t & 63, w = t >> 6;
    int v = (t < NBUCK) ? sm.hist[t] : 0;
    int s = v;
#pragma unroll
    for (int off = 1; off < 64; off <<= 1) {
        int u = __shfl_up(s, off, 64);
        if (lane >= off) s += u;
    }
    if (lane == 63) sm.wsum[w] = s;
    __syncthreads();
    if (t == 0) {
        int run = 0;
#pragma unroll
        for (int i = 0; i < 8; ++i) { int c = sm.wsum[i]; sm.wsum[i] = run; run += c; }
    }
    __syncthreads();
    if (t < NBUCK) {
        int ex = s - v + sm.wsum[w];
        sm.lofs[t] = ex;
        sm.lcur[t] = ex;
        sm.gbase[t] = t * CAPB + (v ? atomicAdd(&cursor[t], v) : 0);
    }
    __syncthreads();
#pragma unroll
    for (int it = 0; it < 8; ++it) {
        int i = t + it * 512;
        if (i < n) {
            int d = d_r[it];
            int b = d >> 8;
            int p = atomicAdd(&sm.lcur[b], 1);
            sm.stage[p] = ((unsigned)s_r[it] << 8) | (unsigned)(d & 255);
            sm.sbuck[p] = (unsigned short)b;
        }
    }
    __syncthreads();
    for (int i = t; i < n; i += 512) {
        int b = sm.sbuck[i];
        packed[sm.gbase[b] + (i - sm.lofs[b])] = sm.stage[i];
    }
}

// ---------------------------------------------------------------------------
// gemm1 body (MFMA): Ah = bf16(X @ W1). 512 thr = 8 waves x 16 rows = 128
// rows/block. X converted in-register to bf16 hi + residual; W1 staged per
// block into LDS as bf16 hi/residual B-fragments (same layout as w2prep).
// 3-product split (hi*hi + lo*hi + hi*lo) keeps ~f32 accuracy.
// ---------------------------------------------------------------------------
__device__ __forceinline__ void gemm_mfma_body(const float* __restrict__ X,
                                               const float* __restrict__ W,
                                               unsigned* __restrict__ Ah, int bid,
                                               unsigned (*w1f)[64][4]) {
    int t = threadIdx.x;
    // build W fragments: slot = ct*4 + ks*2 + p; scattered reads, W L1/L2-hot
    for (int idx = t; idx < 4096; idx += 512) {
        int slot = idx >> 8;
        int ks   = (slot >> 1) & 1;
        int p    = slot & 1;
        int ct   = slot >> 2;
        int l    = (idx >> 2) & 63;
        int j    = idx & 3;
        int k    = 32 * ks + 8 * (l >> 4) + 2 * j;
        int col  = 16 * ct + (l & 15);
        float v0 = W[k * 64 + col];
        float v1 = W[(k + 1) * 64 + col];
        if (p) {
            v0 -= __uint_as_float(bf_rne(v0) << 16);
            v1 -= __uint_as_float(bf_rne(v1) << 16);
        }
        ((unsigned*)w1f)[idx] = pack2(v0, v1);
    }

    int lane = t & 63, wid = t >> 6;
    int g = lane >> 4;
    int wrow0 = bid * 128 + wid * 16;
    int wrow  = wrow0 + (lane & 15);
    bool valid = wrow < NN;
    const float* xp = X + (size_t)wrow * F + 8 * g;
    float4 fz = {0.f, 0.f, 0.f, 0.f};
    float4 f0 = valid ? *(const float4*)(xp)      : fz;   // ks=0, elems 0-3
    float4 f1 = valid ? *(const float4*)(xp + 4)  : fz;   // ks=0, elems 4-7
    float4 f2 = valid ? *(const float4*)(xp + 32) : fz;   // ks=1, elems 0-3
    float4 f3 = valid ? *(const float4*)(xp + 36) : fz;   // ks=1, elems 4-7
    __syncthreads();

    f32x4 ac0 = {0.f,0.f,0.f,0.f}, ac1 = ac0, ac2 = ac0, ac3 = ac0;
#pragma unroll
    for (int ks = 0; ks < 2; ++ks) {
        float4 u0 = ks ? f2 : f0;
        float4 u1 = ks ? f3 : f1;
        uint4 hw;
        hw.x = pack2(u0.x, u0.y);
        hw.y = pack2(u0.z, u0.w);
        hw.z = pack2(u1.x, u1.y);
        hw.w = pack2(u1.z, u1.w);
        uint4 lw;
        lw.x = pack2(u0.x - lo_f(hw.x), u0.y - hi_f(hw.x));
        lw.y = pack2(u0.z - lo_f(hw.y), u0.w - hi_f(hw.y));
        lw.z = pack2(u1.x - lo_f(hw.z), u1.y - hi_f(hw.z));
        lw.w = pack2(u1.z - lo_f(hw.w), u1.w - hi_f(hw.w));
        bf16x8 Ahi = __builtin_bit_cast(bf16x8, hw);
        bf16x8 Alo = __builtin_bit_cast(bf16x8, lw);
#pragma unroll
        for (int ct = 0; ct < 4; ++ct) {
            uint4 bh = *(const uint4*)&w1f[ct * 4 + ks * 2 + 0][lane][0];
            uint4 bl = *(const uint4*)&w1f[ct * 4 + ks * 2 + 1][lane][0];
            bf16x8 Bh_ = __builtin_bit_cast(bf16x8, bh);
            bf16x8 Bl_ = __builtin_bit_cast(bf16x8, bl);
            f32x4& ac = (ct == 0) ? ac0 : (ct == 1) ? ac1 : (ct == 2) ? ac2 : ac3;
            ac = __builtin_amdgcn_mfma_f32_16x16x32_bf16(Ahi, Bh_, ac, 0, 0, 0);
            ac = __builtin_amdgcn_mfma_f32_16x16x32_bf16(Alo, Bh_, ac, 0, 0, 0);
            ac = __builtin_amdgcn_mfma_f32_16x16x32_bf16(Ahi, Bl_, ac, 0, 0, 0);
        }
    }
    // C layout: col = lane&15, row = 4*(lane>>4) + r. Pack col pairs.
#pragma unroll
    for (int ct = 0; ct < 4; ++ct) {
        f32x4 ac = (ct == 0) ? ac0 : (ct == 1) ? ac1 : (ct == 2) ? ac2 : ac3;
#pragma unroll
        for (int r = 0; r < 4; ++r) {
            float val = ac[r];
            float q = __shfl_xor(val, 1, 64);
            int row = wrow0 + 4 * g + r;
            if (!(lane & 1) && row < NN) {
                int colp = 8 * ct + ((lane & 15) >> 1);
                Ah[(size_t)row * 32 + colp] = pack2(val, q);
            }
        }
    }
}

// ---------------------------------------------------------------------------
// W2 fragment precompute (runs once, as one extra block of K1): emits the
// MFMA B-operand layout, bf16 hi (p=0) + bf16 residual (p=1), linear words.
// ---------------------------------------------------------------------------
__device__ __forceinline__ void w2prep_body(const float* __restrict__ W2,
                                            unsigned* __restrict__ w2f) {
    int t = threadIdx.x;
    for (int idx = t; idx < 4096; idx += 512) {
        int slot = idx >> 8;
        int ks   = (slot >> 1) & 1;
        int p    = slot & 1;
        int ct   = slot >> 2;
        int l    = (idx >> 2) & 63;
        int j    = idx & 3;
        int k    = 32 * ks + 8 * (l >> 4) + 2 * j;
        int col  = 16 * ct + (l & 15);
        float v0 = W2[k * 64 + col];
        float v1 = W2[(k + 1) * 64 + col];
        if (p) {
            v0 -= __uint_as_float(bf_rne(v0) << 16);
            v1 -= __uint_as_float(bf_rne(v1) << 16);
        }
        w2f[idx] = pack2(v0, v1);
    }
}

// ---------------------------------------------------------------------------
// node_sort body: per-bucket LDS counting sort to node order; emits row_ptr
// (absolute), deg, dis = rsqrt(deg+1). srt stays bucket-strided.
// packed read ONCE into registers (n <= CAPB = 8*512).
// ---------------------------------------------------------------------------
__device__ __forceinline__ void node_sort_body(const unsigned* __restrict__ packed,
                                               const int* __restrict__ cursor,
                                               int* __restrict__ row_ptr,
                                               int* __restrict__ deg,
                                               float* __restrict__ dis,
                                               int* __restrict__ srt,
                                               int b, NsSmem& sm) {
    int t = threadIdx.x;
    int nbase = b << 8;
    int nloc = min(256, NN - nbase);
    int beg = b * CAPB;
    int n = cursor[b];

    if (t < 256) sm.h[t] = 0;
    __syncthreads();
    unsigned p_r[8];
#pragma unroll
    for (int it = 0; it < 8; ++it) {
        int i = t + it * 512;
        if (i < n) {
            p_r[it] = packed[beg + i];
            atomicAdd(&sm.h[p_r[it] & 255u], 1);
        }
    }
    __syncthreads();
    int lane = t & 63, w = t >> 6;
    int v = 0, s = 0;
    if (t < 256) { v = sm.h[t]; s = v; }
#pragma unroll
    for (int off = 1; off < 64; off <<= 1) {
        int u = __shfl_up(s, off, 64);
        if (lane >= off) s += u;
    }
    if (t < 256 && lane == 63) sm.wsum[w] = s;
    __syncthreads();
    if (t == 0) {
        int run = 0;
#pragma unroll
        for (int i = 0; i < 4; ++i) { int c = sm.wsum[i]; sm.wsum[i] = run; run += c; }
    }
    __syncthreads();
    if (t < 256) {
        int e0 = s - v + sm.wsum[w];
        sm.lcur[t] = e0;
        if (t < nloc) {
            row_ptr[nbase + t] = beg + e0;
            deg[nbase + t]     = v;
            dis[nbase + t]     = rsqrtf((float)v + 1.0f);   // +1 = self-loop
        }
    }
    __syncthreads();
#pragma unroll
    for (int it = 0; it < 8; ++it) {
        int i = t + it * 512;
        if (i < n) {
            unsigned p = p_r[it];
            int pos = atomicAdd(&sm.lcur[p & 255u], 1);
            sm.stage[pos] = (int)(p >> 8);
        }
    }
    __syncthreads();
    for (int i = t; i < n; i += 512) srt[beg + i] = sm.stage[i];
}

// K1: binpack (blocks [0,nbp)) || MFMA gemm1 part A || W2 fragment prep.
__global__ __launch_bounds__(512) void pre_gemm1(const int* __restrict__ src,
                                                 const int* __restrict__ dst, int E,
                                                 int nbp, int* __restrict__ cursor,
                                                 unsigned* __restrict__ packed,
                                                 const float* __restrict__ X,
                                                 const float* __restrict__ W1,
                                                 unsigned* __restrict__ Ah,
                                                 const float* __restrict__ W2,
                                                 unsigned* __restrict__ w2f) {
    __shared__ KSmem sm;
    if ((int)blockIdx.x < nbp)
        binpack_body(src, dst, E, cursor, packed, blockIdx.x, sm.bp);
    else if ((int)blockIdx.x < nbp + G1A)
        gemm_mfma_body(X, W1, Ah, (int)blockIdx.x - nbp, sm.w1f);
    else
        w2prep_body(W2, w2f);
}

// K2: node_sort (blocks [0,NBUCK)) || MFMA gemm1 part B (rest).
__global__ __launch_bounds__(512) void sort_gemm1(const unsigned* __restrict__ packed,
                                                  const int* __restrict__ cursor,
                                                  int* __restrict__ row_ptr,
                                                  int* __restrict__ deg,
                                                  float* __restrict__ dis,
                                                  int* __restrict__ srt,
                                                  const float* __restrict__ X,
                                                  const float* __restrict__ W1,
                                                  unsigned* __restrict__ Ah) {
    __shared__ K2Smem sm;
    if ((int)blockIdx.x < NBUCK)
        node_sort_body(packed, cursor, row_ptr, deg, dis, srt, blockIdx.x, sm.ns);
    else
        gemm_mfma_body(X, W1, Ah, G1A + (int)blockIdx.x - NBUCK, sm.w1f);
}

// ---------------------------------------------------------------------------
// K3: layer-1 aggregate fused with layer-2 transform (MFMA epilogue).
// Gather: 256 thr = 16 nodes x (2 edge-groups x 8 lanes), uint4 rows.
// W2 fragments loaded from precomputed workspace (4 coalesced uint4/thread).
// Epilogue: h staged to swizzled LDS bf16 tile [16 nodes x 64]; each wave
// computes all 16 nodes x its 16-col tile via 4x mfma_f32_16x16x32_bf16
// (hi/residual split keeps W2 at ~f32 precision). Writes Bh = bf16(dis*(h@W2)).
// ---------------------------------------------------------------------------
__global__ __launch_bounds__(256) void agg1_gemm2(const uint4* __restrict__ Ah4,
                                                  const int* __restrict__ row_ptr,
                                                  const int* __restrict__ deg,
                                                  const int* __restrict__ srt,
                                                  const float* __restrict__ dis,
                                                  const float* __restrict__ b1,
                                                  const unsigned* __restrict__ w2fg,
                                                  unsigned* __restrict__ Bh) {
    __shared__ K3Smem sm;
    int t = threadIdx.x;
    // stage precomputed W2 fragments: 1024 uint4, coalesced, L2-resident
#pragma unroll
    for (int i = 0; i < 4; ++i)
        ((uint4*)sm.w2f)[t + 256 * i] = ((const uint4*)w2fg)[t + 256 * i];

    int sub  = t & 7;            // col chunk: cols [8*sub, 8*sub+8)
    int grp  = (t >> 3) & 1;     // edge group
    int node = blockIdx.x * 16 + (t >> 4);
    int beg = row_ptr[node];
    int end = beg + deg[node];
    float di = dis[node];

    float a0, a1, a2, a3, a4, a5, a6, a7;
    uint4 su = Ah4[(size_t)node * 8 + sub];
    if (grp == 0) {
        a0 = di * lo_f(su.x); a1 = di * hi_f(su.x);
        a2 = di * lo_f(su.y); a3 = di * hi_f(su.y);
        a4 = di * lo_f(su.z); a5 = di * hi_f(su.z);
        a6 = di * lo_f(su.w); a7 = di * hi_f(su.w);
    } else {
        a0 = a1 = a2 = a3 = a4 = a5 = a6 = a7 = 0.f;
    }

    int j = beg + grp;
    for (; j + 6 < end; j += 8) {
        int s0 = srt[j], s1 = srt[j + 2], s2 = srt[j + 4], s3 = srt[j + 6];
        float d0 = dis[s0], d1 = dis[s1], d2 = dis[s2], d3 = dis[s3];
        uint4 g0 = Ah4[(size_t)s0 * 8 + sub];
        uint4 g1 = Ah4[(size_t)s1 * 8 + sub];
        uint4 g2 = Ah4[(size_t)s2 * 8 + sub];
        uint4 g3 = Ah4[(size_t)s3 * 8 + sub];
        a0 = fmaf(d0, lo_f(g0.x), fmaf(d1, lo_f(g1.x), fmaf(d2, lo_f(g2.x), fmaf(d3, lo_f(g3.x), a0))));
        a1 = fmaf(d0, hi_f(g0.x), fmaf(d1, hi_f(g1.x), fmaf(d2, hi_f(g2.x), fmaf(d3, hi_f(g3.x), a1))));
        a2 = fmaf(d0, lo_f(g0.y), fmaf(d1, lo_f(g1.y), fmaf(d2, lo_f(g2.y), fmaf(d3, lo_f(g3.y), a2))));
        a3 = fmaf(d0, hi_f(g0.y), fmaf(d1, hi_f(g1.y), fmaf(d2, hi_f(g2.y), fmaf(d3, hi_f(g3.y), a3))));
        a4 = fmaf(d0, lo_f(g0.z), fmaf(d1, lo_f(g1.z), fmaf(d2, lo_f(g2.z), fmaf(d3, lo_f(g3.z), a4))));
        a5 = fmaf(d0, hi_f(g0.z), fmaf(d1, hi_f(g1.z), fmaf(d2, hi_f(g2.z), fmaf(d3, hi_f(g3.z), a5))));
        a6 = fmaf(d0, lo_f(g0.w), fmaf(d1, lo_f(g1.w), fmaf(d2, lo_f(g2.w), fmaf(d3, lo_f(g3.w), a6))));
        a7 = fmaf(d0, hi_f(g0.w), fmaf(d1, hi_f(g1.w), fmaf(d2, hi_f(g2.w), fmaf(d3, hi_f(g3.w), a7))));
    }
    for (; j + 2 < end; j += 4) {
        int s0 = srt[j], s1 = srt[j + 2];
        float d0 = dis[s0], d1 = dis[s1];
        uint4 g0 = Ah4[(size_t)s0 * 8 + sub];
        uint4 g1 = Ah4[(size_t)s1 * 8 + sub];
        a0 = fmaf(d0, lo_f(g0.x), fmaf(d1, lo_f(g1.x), a0));
        a1 = fmaf(d0, hi_f(g0.x), fmaf(d1, hi_f(g1.x), a1));
        a2 = fmaf(d0, lo_f(g0.y), fmaf(d1, lo_f(g1.y), a2));
        a3 = fmaf(d0, hi_f(g0.y), fmaf(d1, hi_f(g1.y), a3));
        a4 = fmaf(d0, lo_f(g0.z), fmaf(d1, lo_f(g1.z), a4));
        a5 = fmaf(d0, hi_f(g0.z), fmaf(d1, hi_f(g1.z), a5));
        a6 = fmaf(d0, lo_f(g0.w), fmaf(d1, lo_f(g1.w), a6));
        a7 = fmaf(d0, hi_f(g0.w), fmaf(d1, hi_f(g1.w), a7));
    }
    for (; j < end; j += 2) {
        int s0 = srt[j];
        float d0 = dis[s0];
        uint4 g0 = Ah4[(size_t)s0 * 8 + sub];
        a0 = fmaf(d0, lo_f(g0.x), a0);
        a1 = fmaf(d0, hi_f(g0.x), a1);
        a2 = fmaf(d0, lo_f(g0.y), a2);
        a3 = fmaf(d0, hi_f(g0.y), a3);
        a4 = fmaf(d0, lo_f(g0.z), a4);
        a5 = fmaf(d0, hi_f(g0.z), a5);
        a6 = fmaf(d0, lo_f(g0.w), a6);
        a7 = fmaf(d0, hi_f(g0.w), a7);
    }
    // combine the two edge-groups (lane ^ 8 within each 16-lane node slice)
    a0 += __shfl_xor(a0, 8, 64); a1 += __shfl_xor(a1, 8, 64);
    a2 += __shfl_xor(a2, 8, 64); a3 += __shfl_xor(a3, 8, 64);
    a4 += __shfl_xor(a4, 8, 64); a5 += __shfl_xor(a5, 8, 64);
    a6 += __shfl_xor(a6, 8, 64); a7 += __shfl_xor(a7, 8, 64);

    float4 bb0 = ((const float4*)b1)[2 * sub];
    float4 bb1 = ((const float4*)b1)[2 * sub + 1];
    float o0 = fmaxf(fmaf(di, a0, bb0.x), 0.f);
    float o1 = fmaxf(fmaf(di, a1, bb0.y), 0.f);
    float o2 = fmaxf(fmaf(di, a2, bb0.z), 0.f);
    float o3 = fmaxf(fmaf(di, a3, bb0.w), 0.f);
    float o4 = fmaxf(fmaf(di, a4, bb1.x), 0.f);
    float o5 = fmaxf(fmaf(di, a5, bb1.y), 0.f);
    float o6 = fmaxf(fmaf(di, a6, bb1.z), 0.f);
    float o7 = fmaxf(fmaf(di, a7, bb1.w), 0.f);

    // stage h (bf16) into swizzled LDS tile; grp0 half writes
    int node15 = t >> 4;
    if (!(t & 8)) {
        int unit = sub ^ (node15 & 7);
        uint4 hv;
        hv.x = pack2(o0, o1);
        hv.y = pack2(o2, o3);
        hv.z = pack2(o4, o5);
        hv.w = pack2(o6, o7);
        *(uint4*)&sm.hbuf[node15 * 32 + unit * 4] = hv;
        if (sub == 0) sm.dis_s[node15] = di;
    }
    __syncthreads();

    // ---- MFMA h @ W2: wave ct covers cols [16ct,16ct+16), all 16 nodes ----
    int lane = t & 63, ct = t >> 6;
    int row = lane & 15, g = lane >> 4;
    f32x4 acc = {0.f, 0.f, 0.f, 0.f};
#pragma unroll
    for (int ks = 0; ks < 2; ++ks) {
        int unit = (4 * ks + g) ^ (row & 7);
        uint4 araw = *(const uint4*)&sm.hbuf[row * 32 + unit * 4];
        uint4 bhr  = *(const uint4*)&sm.w2f[ct * 4 + ks * 2 + 0][lane][0];
        uint4 blr  = *(const uint4*)&sm.w2f[ct * 4 + ks * 2 + 1][lane][0];
        bf16x8 A  = __builtin_bit_cast(bf16x8, araw);
        bf16x8 Bh_ = __builtin_bit_cast(bf16x8, bhr);
        bf16x8 Bl_ = __builtin_bit_cast(bf16x8, blr);
        acc = __builtin_amdgcn_mfma_f32_16x16x32_bf16(A, Bh_, acc, 0, 0, 0);
        acc = __builtin_amdgcn_mfma_f32_16x16x32_bf16(A, Bl_, acc, 0, 0, 0);
    }
    // C layout: col = lane&15, row(node) = 4*(lane>>4) + r
    int nbase16 = blockIdx.x * 16;
#pragma unroll
    for (int r = 0; r < 4; ++r) {
        int nd = 4 * g + r;
        float val = acc[r] * sm.dis_s[nd];
        float q = __shfl_xor(val, 1, 64);
        if (!(lane & 1)) {
            int colp = 8 * ct + ((lane & 15) >> 1);
            Bh[(size_t)(nbase16 + nd) * 32 + colp] = pack2(val, q);
        }
    }
}

// ---------------------------------------------------------------------------
// K4: layer-2 aggregate over pre-scaled bf16 Bh rows (no per-edge dis!),
// same 16-node x (2 grp x 8 lane) structure, f32 float4 output.
// ---------------------------------------------------------------------------
__global__ __launch_bounds__(256) void agg_out(const uint4* __restrict__ Bs4,
                                               const int* __restrict__ row_ptr,
                                               const int* __restrict__ deg,
                                               const int* __restrict__ srt,
                                               const float* __restrict__ dis,
                                               const float* __restrict__ bias,
                                               float* __restrict__ outp) {
    int t = threadIdx.x;
    int sub  = t & 7;
    int grp  = (t >> 3) & 1;
    int node = blockIdx.x * 16 + (t >> 4);
    int beg = row_ptr[node];
    int end = beg + deg[node];
    float di = dis[node];

    float a0, a1, a2, a3, a4, a5, a6, a7;
    uint4 su = Bs4[(size_t)node * 8 + sub];     // already dis-scaled
    if (grp == 0) {
        a0 = lo_f(su.x); a1 = hi_f(su.x);
        a2 = lo_f(su.y); a3 = hi_f(su.y);
        a4 = lo_f(su.z); a5 = hi_f(su.z);
        a6 = lo_f(su.w); a7 = hi_f(su.w);
    } else {
        a0 = a1 = a2 = a3 = a4 = a5 = a6 = a7 = 0.f;
    }

    int j = beg + grp;
    for (; j + 6 < end; j += 8) {
        int s0 = srt[j], s1 = srt[j + 2], s2 = srt[j + 4], s3 = srt[j + 6];
        uint4 g0 = Bs4[(size_t)s0 * 8 + sub];
        uint4 g1 = Bs4[(size_t)s1 * 8 + sub];
        uint4 g2 = Bs4[(size_t)s2 * 8 + sub];
        uint4 g3 = Bs4[(size_t)s3 * 8 + sub];
        a0 += (lo_f(g0.x) + lo_f(g1.x)) + (lo_f(g2.x) + lo_f(g3.x));
        a1 += (hi_f(g0.x) + hi_f(g1.x)) + (hi_f(g2.x) + hi_f(g3.x));
        a2 += (lo_f(g0.y) + lo_f(g1.y)) + (lo_f(g2.y) + lo_f(g3.y));
        a3 += (hi_f(g0.y) + hi_f(g1.y)) + (hi_f(g2.y) + hi_f(g3.y));
        a4 += (lo_f(g0.z) + lo_f(g1.z)) + (lo_f(g2.z) + lo_f(g3.z));
        a5 += (hi_f(g0.z) + hi_f(g1.z)) + (hi_f(g2.z) + hi_f(g3.z));
        a6 += (lo_f(g0.w) + lo_f(g1.w)) + (lo_f(g2.w) + lo_f(g3.w));
        a7 += (hi_f(g0.w) + hi_f(g1.w)) + (hi_f(g2.w) + hi_f(g3.w));
    }
    for (; j + 2 < end; j += 4) {
        int s0 = srt[j], s1 = srt[j + 2];
        uint4 g0 = Bs4[(size_t)s0 * 8 + sub];
        uint4 g1 = Bs4[(size_t)s1 * 8 + sub];
        a0 += lo_f(g0.x) + lo_f(g1.x);
        a1 += hi_f(g0.x) + hi_f(g1.x);
        a2 += lo_f(g0.y) + lo_f(g1.y);
        a3 += hi_f(g0.y) + hi_f(g1.y);
        a4 += lo_f(g0.z) + lo_f(g1.z);
        a5 += hi_f(g0.z) + hi_f(g1.z);
        a6 += lo_f(g0.w) + lo_f(g1.w);
        a7 += hi_f(g0.w) + hi_f(g1.w);
    }
    for (; j < end; j += 2) {
        int s0 = srt[j];
        uint4 g0 = Bs4[(size_t)s0 * 8 + sub];
        a0 += lo_f(g0.x); a1 += hi_f(g0.x);
        a2 += lo_f(g0.y); a3 += hi_f(g0.y);
        a4 += lo_f(g0.z); a5 += hi_f(g0.z);
        a6 += lo_f(g0.w); a7 += hi_f(g0.w);
    }
    a0 += __shfl_xor(a0, 8, 64); a1 += __shfl_xor(a1, 8, 64);
    a2 += __shfl_xor(a2, 8, 64); a3 += __shfl_xor(a3, 8, 64);
    a4 += __shfl_xor(a4, 8, 64); a5 += __shfl_xor(a5, 8, 64);
    a6 += __shfl_xor(a6, 8, 64); a7 += __shfl_xor(a7, 8, 64);

    float4 bb0 = ((const float4*)bias)[2 * sub];
    float4 bb1 = ((const float4*)bias)[2 * sub + 1];
    float4 o;
    if (grp == 0) {
        o.x = fmaf(di, a0, bb0.x);
        o.y = fmaf(di, a1, bb0.y);
        o.z = fmaf(di, a2, bb0.z);
        o.w = fmaf(di, a3, bb0.w);
        ((float4*)outp)[(size_t)node * 16 + 2 * sub] = o;
    } else {
        o.x = fmaf(di, a4, bb1.x);
        o.y = fmaf(di, a5, bb1.y);
        o.z = fmaf(di, a6, bb1.z);
        o.w = fmaf(di, a7, bb1.w);
        ((float4*)outp)[(size_t)node * 16 + 2 * sub + 1] = o;
    }
}

extern "C" void kernel_launch(void* const* d_in, const int* in_sizes, int n_in,
                              void* d_out, int out_size, void* d_ws, size_t ws_size,
                              hipStream_t stream) {
    const float* x  = (const float*)d_in[0];
    const int*   ei = (const int*)d_in[1];   // [2,E]: src = ei[0:E], dst = ei[E:2E]
    const float* W1 = (const float*)d_in[2];
    const float* b1 = (const float*)d_in[3];
    const float* W2 = (const float*)d_in[4];
    const float* b2 = (const float*)d_in[5];
    float* out = (float*)d_out;
    int E = in_sizes[1] / 2;
    const int* src = ei;
    const int* dst = ei + E;

    int*      ws_i    = (int*)d_ws;
    int*      cursor  = ws_i + O_CURSOR;
    int*      row_ptr = ws_i + O_ROWPTR;
    int*      deg     = ws_i + O_DEG;
    float*    dis     = (float*)(ws_i + O_DIS);
    unsigned* packed  = (unsigned*)(ws_i + O_PACKED);
    int*      srt     = ws_i + O_SRT;
    unsigned* Ah      = (unsigned*)(ws_i + O_AH);
    unsigned* Bh      = (unsigned*)(ws_i + O_BH);
    unsigned* w2f     = (unsigned*)(ws_i + O_W2F);

    int nbp = (E + TILE - 1) / TILE;

    (void)hipMemsetAsync(cursor, 0, NBUCK * sizeof(int), stream);
    // K1: binpack (first nbp blocks) || MFMA gemm1 blocks [0, G1A) || W2 prep
    pre_gemm1<<<nbp + G1A + 1, 512, 0, stream>>>(src, dst, E, nbp, cursor, packed,
                                                 x, W1, Ah, W2, w2f);
    // K2: node_sort (first NBUCK blocks) || MFMA gemm1 blocks [G1A, NBLKG)
    sort_gemm1<<<NBUCK + (NBLKG - G1A), 512, 0, stream>>>(packed, cursor, row_ptr,
                                                          deg, dis, srt, x, W1, Ah);
    // K3: layer-1 aggregate + ReLU + fused layer-2 MFMA gemm -> bf16 Bh
    agg1_gemm2<<<NN / 16, 256, 0, stream>>>((const uint4*)Ah, row_ptr, deg, srt,
                                            dis, b1, w2f, Bh);
    // K4: layer-2 aggregate -> f32 out
    agg_out<<<NN / 16, 256, 0, stream>>>((const uint4*)Bh, row_ptr, deg, srt,
                                         dis, b2, out);
}

// Round 7
// 181.070 us; speedup vs baseline: 1.1111x; 1.0091x over previous
//
#include <hip/hip_runtime.h>

#define NN    100000   // N_NODES
#define F     64       // feature dim (= hidden dim)
#define NBUCK 391      // ceil(NN/256) buckets of 256 nodes
#define CAPB  4096     // per-bucket edge capacity (mean 3197+pad<=256, 11-sigma margin)
#define TILE  4096     // edges per binpack tile
#define NBLKG 782      // ceil(NN/128) MFMA gemm1 blocks (128 rows each)
#define G1A   400      // gemm1 blocks placed in K1 (rest overlap node_sort in K2)

// workspace offsets (4-byte elements)
#define O_CURSOR 0          // int[391]
#define O_ROWPTR 512        // int[100000]  absolute index into srt
#define O_DEG    100864     // int[100000]
#define O_DIS    201216     // float[100000]
#define O_PACKED 301568     // uint[391*4096]
#define O_SRT    1903104    // int[391*4096 + 64]  (stores BYTE offsets = node*128)
#define O_AH     3504768    // uint[NN*32]: bf16-packed layer-1 A rows (128 B/row)
#define O_BH     6704768    // uint[NN*32]: bf16-packed layer-2 rows dis*(h@W2)
#define O_W2F    9904768    // uint[4096]: W2 bf16 hi/residual MFMA B-fragments

typedef __attribute__((ext_vector_type(8))) short bf16x8;
typedef __attribute__((ext_vector_type(4))) float f32x4;
typedef __attribute__((ext_vector_type(2))) float f32x2;

// ---- bf16 pack/unpack (RNE; values finite) --------------------------------
__device__ __forceinline__ unsigned bf_rne(float x) {
    unsigned u = __float_as_uint(x);
    return (u + 0x7FFFu + ((u >> 16) & 1u)) >> 16;
}
__device__ __forceinline__ unsigned pack2(float lo, float hi) {
    return bf_rne(lo) | (bf_rne(hi) << 16);
}
__device__ __forceinline__ float lo_f(unsigned u) { return __uint_as_float(u << 16); }
__device__ __forceinline__ float hi_f(unsigned u) { return __uint_as_float(u & 0xFFFF0000u); }
// unpack bf16 pair -> f32x2 (feeds v_pk_fma_f32 / v_pk_add_f32)
__device__ __forceinline__ f32x2 up2(unsigned u) {
    f32x2 r = {__uint_as_float(u << 16), __uint_as_float(u & 0xFFFF0000u)};
    return r;
}

// ---- shared-memory unions (per-block exclusive) ----------------------------
struct BpSmem {
    int hist[NBUCK], lofs[NBUCK], gbase[NBUCK], lcur[NBUCK];
    int wsum[8];
    unsigned stage[TILE];                     // 16 KB
    unsigned short sbuck[TILE];               // 8 KB
};                                            // 30864 B
union KSmem {
    BpSmem bp;
    unsigned w1f[16][64][4];                  // 16 KB MFMA B-fragments of W1
};
struct NsSmem {
    int h[256], lcur[256], wsum[4], ptot;
    int stage[CAPB];                          // 16 KB
};
union K2Smem {
    NsSmem ns;
    unsigned w1f[16][64][4];                  // 16 KB
};
// K3: W2 bf16 hi/lo in B-fragment order + swizzled h tile + dis cache
struct K3Smem {
    unsigned w2f[16][64][4];   // slot = ct*4 + ks*2 + p (p: 0=hi,1=residual); 16 KB
    unsigned hbuf[16 * 32];    // bf16 h rows, XOR-swizzled 16B units; 2 KB
    float dis_s[16];
};                             // 18496 B

// ---------------------------------------------------------------------------
// binpack body (unchanged): tile counting-sort into 391 bucket-strided
// regions. packed = (src<<8) | (dst & 255). 512 threads, regs-retained.
// ---------------------------------------------------------------------------
__device__ __forceinline__ void binpack_body(const int* __restrict__ src,
                                             const int* __restrict__ dst, int E,
                                             int* __restrict__ cursor,
                                             unsigned* __restrict__ packed,
                                             int bid, BpSmem& sm) {
    int t  = threadIdx.x;
    int t0 = bid * TILE;
    int n  = min(TILE, E - t0);

    if (t < NBUCK) sm.hist[t] = 0;
    __syncthreads();
    int d_r[8], s_r[8];
#pragma unroll
    for (int it = 0; it < 8; ++it) {
        int i = t + it * 512;
        if (i < n) {
            d_r[it] = dst[t0 + i];
            s_r[it] = src[t0 + i];
            atomicAdd(&sm.hist[d_r[it] >> 8], 1);
        }
    }
    __syncthreads();
    int lane = t & 63, w = t >> 6;
    int v = (t < NBUCK) ? sm.hist[t] : 0;
    int s = v;
#pragma unroll
    for (int off = 1; off < 64; off <<= 1) {
        int u = __shfl_up(s, off, 64);
        if (lane >= off) s += u;
    }
    if (lane == 63) sm.wsum[w] = s;
    __syncthreads();
    if (t == 0) {
        int run = 0;
#pragma unroll
        for (int i = 0; i < 8; ++i) { int c = sm.wsum[i]; sm.wsum[i] = run; run += c; }
    }
    __syncthreads();
    if (t < NBUCK) {
        int ex = s - v + sm.wsum[w];
        sm.lofs[t] = ex;
        sm.lcur[t] = ex;
        sm.gbase[t] = t * CAPB + (v ? atomicAdd(&cursor[t], v) : 0);
    }
    __syncthreads();
#pragma unroll
    for (int it = 0; it < 8; ++it) {
        int i = t + it * 512;
        if (i < n) {
            int d = d_r[it];
            int b = d >> 8;
            int p = atomicAdd(&sm.lcur[b], 1);
            sm.stage[p] = ((unsigned)s_r[it] << 8) | (unsigned)(d & 255);
            sm.sbuck[p] = (unsigned short)b;
        }
    }
    __syncthreads();
    for (int i = t; i < n; i += 512) {
        int b = sm.sbuck[i];
        packed[sm.gbase[b] + (i - sm.lofs[b])] = sm.stage[i];
    }
}

// ---------------------------------------------------------------------------
// gemm1 body (MFMA, unchanged): Ah = bf16(X @ W1). 8 waves x 16 rows.
// ---------------------------------------------------------------------------
__device__ __forceinline__ void gemm_mfma_body(const float* __restrict__ X,
                                               const float* __restrict__ W,
                                               unsigned* __restrict__ Ah, int bid,
                                               unsigned (*w1f)[64][4]) {
    int t = threadIdx.x;
    for (int idx = t; idx < 4096; idx += 512) {
        int slot = idx >> 8;
        int ks   = (slot >> 1) & 1;
        int p    = slot & 1;
        int ct   = slot >> 2;
        int l    = (idx >> 2) & 63;
        int j    = idx & 3;
        int k    = 32 * ks + 8 * (l >> 4) + 2 * j;
        int col  = 16 * ct + (l & 15);
        float v0 = W[k * 64 + col];
        float v1 = W[(k + 1) * 64 + col];
        if (p) {
            v0 -= __uint_as_float(bf_rne(v0) << 16);
            v1 -= __uint_as_float(bf_rne(v1) << 16);
        }
        ((unsigned*)w1f)[idx] = pack2(v0, v1);
    }

    int lane = t & 63, wid = t >> 6;
    int g = lane >> 4;
    int wrow0 = bid * 128 + wid * 16;
    int wrow  = wrow0 + (lane & 15);
    bool valid = wrow < NN;
    const float* xp = X + (size_t)wrow * F + 8 * g;
    float4 fz = {0.f, 0.f, 0.f, 0.f};
    float4 f0 = valid ? *(const float4*)(xp)      : fz;
    float4 f1 = valid ? *(const float4*)(xp + 4)  : fz;
    float4 f2 = valid ? *(const float4*)(xp + 32) : fz;
    float4 f3 = valid ? *(const float4*)(xp + 36) : fz;
    __syncthreads();

    f32x4 ac0 = {0.f,0.f,0.f,0.f}, ac1 = ac0, ac2 = ac0, ac3 = ac0;
#pragma unroll
    for (int ks = 0; ks < 2; ++ks) {
        float4 u0 = ks ? f2 : f0;
        float4 u1 = ks ? f3 : f1;
        uint4 hw;
        hw.x = pack2(u0.x, u0.y);
        hw.y = pack2(u0.z, u0.w);
        hw.z = pack2(u1.x, u1.y);
        hw.w = pack2(u1.z, u1.w);
        uint4 lw;
        lw.x = pack2(u0.x - lo_f(hw.x), u0.y - hi_f(hw.x));
        lw.y = pack2(u0.z - lo_f(hw.y), u0.w - hi_f(hw.y));
        lw.z = pack2(u1.x - lo_f(hw.z), u1.y - hi_f(hw.z));
        lw.w = pack2(u1.z - lo_f(hw.w), u1.w - hi_f(hw.w));
        bf16x8 Ahi = __builtin_bit_cast(bf16x8, hw);
        bf16x8 Alo = __builtin_bit_cast(bf16x8, lw);
#pragma unroll
        for (int ct = 0; ct < 4; ++ct) {
            uint4 bh = *(const uint4*)&w1f[ct * 4 + ks * 2 + 0][lane][0];
            uint4 bl = *(const uint4*)&w1f[ct * 4 + ks * 2 + 1][lane][0];
            bf16x8 Bh_ = __builtin_bit_cast(bf16x8, bh);
            bf16x8 Bl_ = __builtin_bit_cast(bf16x8, bl);
            f32x4& ac = (ct == 0) ? ac0 : (ct == 1) ? ac1 : (ct == 2) ? ac2 : ac3;
            ac = __builtin_amdgcn_mfma_f32_16x16x32_bf16(Ahi, Bh_, ac, 0, 0, 0);
            ac = __builtin_amdgcn_mfma_f32_16x16x32_bf16(Alo, Bh_, ac, 0, 0, 0);
            ac = __builtin_amdgcn_mfma_f32_16x16x32_bf16(Ahi, Bl_, ac, 0, 0, 0);
        }
    }
#pragma unroll
    for (int ct = 0; ct < 4; ++ct) {
        f32x4 ac = (ct == 0) ? ac0 : (ct == 1) ? ac1 : (ct == 2) ? ac2 : ac3;
#pragma unroll
        for (int r = 0; r < 4; ++r) {
            float val = ac[r];
            float q = __shfl_xor(val, 1, 64);
            int row = wrow0 + 4 * g + r;
            if (!(lane & 1) && row < NN) {
                int colp = 8 * ct + ((lane & 15) >> 1);
                Ah[(size_t)row * 32 + colp] = pack2(val, q);
            }
        }
    }
}

// ---------------------------------------------------------------------------
// W2 fragment precompute (unchanged).
// ---------------------------------------------------------------------------
__device__ __forceinline__ void w2prep_body(const float* __restrict__ W2,
                                            unsigned* __restrict__ w2f) {
    int t = threadIdx.x;
    for (int idx = t; idx < 4096; idx += 512) {
        int slot = idx >> 8;
        int ks   = (slot >> 1) & 1;
        int p    = slot & 1;
        int ct   = slot >> 2;
        int l    = (idx >> 2) & 63;
        int j    = idx & 3;
        int k    = 32 * ks + 8 * (l >> 4) + 2 * j;
        int col  = 16 * ct + (l & 15);
        float v0 = W2[k * 64 + col];
        float v1 = W2[(k + 1) * 64 + col];
        if (p) {
            v0 -= __uint_as_float(bf_rne(v0) << 16);
            v1 -= __uint_as_float(bf_rne(v1) << 16);
        }
        w2f[idx] = pack2(v0, v1);
    }
}

// ---------------------------------------------------------------------------
// node_sort body: per-bucket counting sort; node edge lists PADDED to 2-edge
// alignment (scan over padded degs) and srt stores BYTE offsets (node*128).
// ---------------------------------------------------------------------------
__device__ __forceinline__ void node_sort_body(const unsigned* __restrict__ packed,
                                               const int* __restrict__ cursor,
                                               int* __restrict__ row_ptr,
                                               int* __restrict__ deg,
                                               float* __restrict__ dis,
                                               int* __restrict__ srt,
                                               int b, NsSmem& sm) {
    int t = threadIdx.x;
    int nbase = b << 8;
    int nloc = min(256, NN - nbase);
    int beg = b * CAPB;
    int n = cursor[b];

    if (t < 256) sm.h[t] = 0;
    __syncthreads();
    unsigned p_r[8];
#pragma unroll
    for (int it = 0; it < 8; ++it) {
        int i = t + it * 512;
        if (i < n) {
            p_r[it] = packed[beg + i];
            atomicAdd(&sm.h[p_r[it] & 255u], 1);
        }
    }
    __syncthreads();
    int lane = t & 63, w = t >> 6;
    int v = 0, pd = 0, s = 0;
    if (t < 256) { v = sm.h[t]; pd = (v + 1) & ~1; s = pd; }
#pragma unroll
    for (int off = 1; off < 64; off <<= 1) {
        int u = __shfl_up(s, off, 64);
        if (lane >= off) s += u;
    }
    if (t < 256 && lane == 63) sm.wsum[w] = s;
    __syncthreads();
    if (t == 0) {
        int run = 0;
#pragma unroll
        for (int i = 0; i < 4; ++i) { int c = sm.wsum[i]; sm.wsum[i] = run; run += c; }
    }
    __syncthreads();
    if (t < 256) {
        int e0 = s - pd + sm.wsum[w];
        sm.lcur[t] = e0;
        if (t < nloc) {
            row_ptr[nbase + t] = beg + e0;
            deg[nbase + t]     = v;
            dis[nbase + t]     = rsqrtf((float)v + 1.0f);   // +1 = self-loop
        }
        if (t == nloc - 1) sm.ptot = e0 + pd;
    }
    __syncthreads();
#pragma unroll
    for (int it = 0; it < 8; ++it) {
        int i = t + it * 512;
        if (i < n) {
            unsigned p = p_r[it];
            int pos = atomicAdd(&sm.lcur[p & 255u], 1);
            sm.stage[pos] = (int)((p >> 8) << 7);   // byte offset = src*128
        }
    }
    __syncthreads();
    int ptot = sm.ptot;
    for (int i = t; i < ptot; i += 512) srt[beg + i] = sm.stage[i];
}

// K1: binpack (blocks [0,nbp)) || MFMA gemm1 part A || W2 fragment prep.
__global__ __launch_bounds__(512) void pre_gemm1(const int* __restrict__ src,
                                                 const int* __restrict__ dst, int E,
                                                 int nbp, int* __restrict__ cursor,
                                                 unsigned* __restrict__ packed,
                                                 const float* __restrict__ X,
                                                 const float* __restrict__ W1,
                                                 unsigned* __restrict__ Ah,
                                                 const float* __restrict__ W2,
                                                 unsigned* __restrict__ w2f) {
    __shared__ KSmem sm;
    if ((int)blockIdx.x < nbp)
        binpack_body(src, dst, E, cursor, packed, blockIdx.x, sm.bp);
    else if ((int)blockIdx.x < nbp + G1A)
        gemm_mfma_body(X, W1, Ah, (int)blockIdx.x - nbp, sm.w1f);
    else
        w2prep_body(W2, w2f);
}

// K2: node_sort (blocks [0,NBUCK)) || MFMA gemm1 part B (rest).
__global__ __launch_bounds__(512) void sort_gemm1(const unsigned* __restrict__ packed,
                                                  const int* __restrict__ cursor,
                                                  int* __restrict__ row_ptr,
                                                  int* __restrict__ deg,
                                                  float* __restrict__ dis,
                                                  int* __restrict__ srt,
                                                  const float* __restrict__ X,
                                                  const float* __restrict__ W1,
                                                  unsigned* __restrict__ Ah) {
    __shared__ K2Smem sm;
    if ((int)blockIdx.x < NBUCK)
        node_sort_body(packed, cursor, row_ptr, deg, dis, srt, blockIdx.x, sm.ns);
    else
        gemm_mfma_body(X, W1, Ah, G1A + (int)blockIdx.x - NBUCK, sm.w1f);
}

// ---------------------------------------------------------------------------
// K3: layer-1 aggregate (half-split groups, byte-offset srt, int2 index
// loads, packed f32x2 FMA) fused with layer-2 MFMA transform.
// ---------------------------------------------------------------------------
__global__ __launch_bounds__(256) void agg1_gemm2(const unsigned* __restrict__ AhW,
                                                  const int* __restrict__ row_ptr,
                                                  const int* __restrict__ deg,
                                                  const int* __restrict__ srt,
                                                  const float* __restrict__ dis,
                                                  const float* __restrict__ b1,
                                                  const unsigned* __restrict__ w2fg,
                                                  unsigned* __restrict__ Bh) {
    __shared__ K3Smem sm;
    int t = threadIdx.x;
#pragma unroll
    for (int i = 0; i < 4; ++i)
        ((uint4*)sm.w2f)[t + 256 * i] = ((const uint4*)w2fg)[t + 256 * i];

    const char* baseA = (const char*)AhW;
    int sub  = t & 7;            // col chunk: cols [8*sub, 8*sub+8)
    int grp  = (t >> 3) & 1;     // edge half
    int soff = sub * 16;
    int node = blockIdx.x * 16 + (t >> 4);
    int cnt = deg[node];
    int beg = row_ptr[node];
    float di = dis[node];

    f32x2 A0, A1, A2, A3;
    if (grp == 0) {
        uint4 su = *(const uint4*)(baseA + ((size_t)node * 128 + soff));
        A0 = f32x2{di * lo_f(su.x), di * hi_f(su.x)};
        A1 = f32x2{di * lo_f(su.y), di * hi_f(su.y)};
        A2 = f32x2{di * lo_f(su.z), di * hi_f(su.z)};
        A3 = f32x2{di * lo_f(su.w), di * hi_f(su.w)};
    } else {
        A0 = A1 = A2 = A3 = f32x2{0.f, 0.f};
    }

    int h  = min(cnt, ((cnt >> 1) + 1) & ~1);          // 2-aligned split
    int jb = beg + (grp ? h : 0);
    int je = jb + (grp ? (cnt - h) : h);
    for (; jb + 4 <= je; jb += 4) {
        int2 sa = *(const int2*)&srt[jb];
        int2 sb = *(const int2*)&srt[jb + 2];
        float d0 = dis[(unsigned)sa.x >> 7];
        float d1 = dis[(unsigned)sa.y >> 7];
        float d2 = dis[(unsigned)sb.x >> 7];
        float d3 = dis[(unsigned)sb.y >> 7];
        uint4 g0 = *(const uint4*)(baseA + (sa.x + soff));
        uint4 g1 = *(const uint4*)(baseA + (sa.y + soff));
        uint4 g2 = *(const uint4*)(baseA + (sb.x + soff));
        uint4 g3 = *(const uint4*)(baseA + (sb.y + soff));
        f32x2 dd0 = {d0, d0}, dd1 = {d1, d1}, dd2 = {d2, d2}, dd3 = {d3, d3};
        A0 = __builtin_elementwise_fma(dd0, up2(g0.x), A0);
        A1 = __builtin_elementwise_fma(dd0, up2(g0.y), A1);
        A2 = __builtin_elementwise_fma(dd0, up2(g0.z), A2);
        A3 = __builtin_elementwise_fma(dd0, up2(g0.w), A3);
        A0 = __builtin_elementwise_fma(dd1, up2(g1.x), A0);
        A1 = __builtin_elementwise_fma(dd1, up2(g1.y), A1);
        A2 = __builtin_elementwise_fma(dd1, up2(g1.z), A2);
        A3 = __builtin_elementwise_fma(dd1, up2(g1.w), A3);
        A0 = __builtin_elementwise_fma(dd2, up2(g2.x), A0);
        A1 = __builtin_elementwise_fma(dd2, up2(g2.y), A1);
        A2 = __builtin_elementwise_fma(dd2, up2(g2.z), A2);
        A3 = __builtin_elementwise_fma(dd2, up2(g2.w), A3);
        A0 = __builtin_elementwise_fma(dd3, up2(g3.x), A0);
        A1 = __builtin_elementwise_fma(dd3, up2(g3.y), A1);
        A2 = __builtin_elementwise_fma(dd3, up2(g3.z), A2);
        A3 = __builtin_elementwise_fma(dd3, up2(g3.w), A3);
    }
    for (; jb + 2 <= je; jb += 2) {
        int2 sa = *(const int2*)&srt[jb];
        float d0 = dis[(unsigned)sa.x >> 7];
        float d1 = dis[(unsigned)sa.y >> 7];
        uint4 g0 = *(const uint4*)(baseA + (sa.x + soff));
        uint4 g1 = *(const uint4*)(baseA + (sa.y + soff));
        f32x2 dd0 = {d0, d0}, dd1 = {d1, d1};
        A0 = __builtin_elementwise_fma(dd0, up2(g0.x), A0);
        A1 = __builtin_elementwise_fma(dd0, up2(g0.y), A1);
        A2 = __builtin_elementwise_fma(dd0, up2(g0.z), A2);
        A3 = __builtin_elementwise_fma(dd0, up2(g0.w), A3);
        A0 = __builtin_elementwise_fma(dd1, up2(g1.x), A0);
        A1 = __builtin_elementwise_fma(dd1, up2(g1.y), A1);
        A2 = __builtin_elementwise_fma(dd1, up2(g1.z), A2);
        A3 = __builtin_elementwise_fma(dd1, up2(g1.w), A3);
    }
    if (jb < je) {
        int sa = srt[jb];
        float d0 = dis[(unsigned)sa >> 7];
        uint4 g0 = *(const uint4*)(baseA + (sa + soff));
        f32x2 dd0 = {d0, d0};
        A0 = __builtin_elementwise_fma(dd0, up2(g0.x), A0);
        A1 = __builtin_elementwise_fma(dd0, up2(g0.y), A1);
        A2 = __builtin_elementwise_fma(dd0, up2(g0.z), A2);
        A3 = __builtin_elementwise_fma(dd0, up2(g0.w), A3);
    }
    float a0 = A0.x, a1 = A0.y, a2 = A1.x, a3 = A1.y;
    float a4 = A2.x, a5 = A2.y, a6 = A3.x, a7 = A3.y;
    a0 += __shfl_xor(a0, 8, 64); a1 += __shfl_xor(a1, 8, 64);
    a2 += __shfl_xor(a2, 8, 64); a3 += __shfl_xor(a3, 8, 64);
    a4 += __shfl_xor(a4, 8, 64); a5 += __shfl_xor(a5, 8, 64);
    a6 += __shfl_xor(a6, 8, 64); a7 += __shfl_xor(a7, 8, 64);

    float4 bb0 = ((const float4*)b1)[2 * sub];
    float4 bb1 = ((const float4*)b1)[2 * sub + 1];
    float o0 = fmaxf(fmaf(di, a0, bb0.x), 0.f);
    float o1 = fmaxf(fmaf(di, a1, bb0.y), 0.f);
    float o2 = fmaxf(fmaf(di, a2, bb0.z), 0.f);
    float o3 = fmaxf(fmaf(di, a3, bb0.w), 0.f);
    float o4 = fmaxf(fmaf(di, a4, bb1.x), 0.f);
    float o5 = fmaxf(fmaf(di, a5, bb1.y), 0.f);
    float o6 = fmaxf(fmaf(di, a6, bb1.z), 0.f);
    float o7 = fmaxf(fmaf(di, a7, bb1.w), 0.f);

    // stage h (bf16) into swizzled LDS tile; grp0 half writes
    int node15 = t >> 4;
    if (!(t & 8)) {
        int unit = sub ^ (node15 & 7);
        uint4 hv;
        hv.x = pack2(o0, o1);
        hv.y = pack2(o2, o3);
        hv.z = pack2(o4, o5);
        hv.w = pack2(o6, o7);
        *(uint4*)&sm.hbuf[node15 * 32 + unit * 4] = hv;
        if (sub == 0) sm.dis_s[node15] = di;
    }
    __syncthreads();

    // ---- MFMA h @ W2: wave ct covers cols [16ct,16ct+16), all 16 nodes ----
    int lane = t & 63, ct = t >> 6;
    int row = lane & 15, g = lane >> 4;
    f32x4 acc = {0.f, 0.f, 0.f, 0.f};
#pragma unroll
    for (int ks = 0; ks < 2; ++ks) {
        int unit = (4 * ks + g) ^ (row & 7);
        uint4 araw = *(const uint4*)&sm.hbuf[row * 32 + unit * 4];
        uint4 bhr  = *(const uint4*)&sm.w2f[ct * 4 + ks * 2 + 0][lane][0];
        uint4 blr  = *(const uint4*)&sm.w2f[ct * 4 + ks * 2 + 1][lane][0];
        bf16x8 A  = __builtin_bit_cast(bf16x8, araw);
        bf16x8 Bh_ = __builtin_bit_cast(bf16x8, bhr);
        bf16x8 Bl_ = __builtin_bit_cast(bf16x8, blr);
        acc = __builtin_amdgcn_mfma_f32_16x16x32_bf16(A, Bh_, acc, 0, 0, 0);
        acc = __builtin_amdgcn_mfma_f32_16x16x32_bf16(A, Bl_, acc, 0, 0, 0);
    }
    // C layout: col = lane&15, row(node) = 4*(lane>>4) + r
    int nbase16 = blockIdx.x * 16;
#pragma unroll
    for (int r = 0; r < 4; ++r) {
        int nd = 4 * g + r;
        float val = acc[r] * sm.dis_s[nd];
        float q = __shfl_xor(val, 1, 64);
        if (!(lane & 1)) {
            int colp = 8 * ct + ((lane & 15) >> 1);
            Bh[(size_t)(nbase16 + nd) * 32 + colp] = pack2(val, q);
        }
    }
}

// ---------------------------------------------------------------------------
// K4: layer-2 aggregate over pre-scaled bf16 Bh rows; half-split groups,
// byte-offset srt, int2 index loads, packed f32x2 adds. f32 float4 output.
// ---------------------------------------------------------------------------
__global__ __launch_bounds__(256) void agg_out(const unsigned* __restrict__ BsW,
                                               const int* __restrict__ row_ptr,
                                               const int* __restrict__ deg,
                                               const int* __restrict__ srt,
                                               const float* __restrict__ dis,
                                               const float* __restrict__ bias,
                                               float* __restrict__ outp) {
    int t = threadIdx.x;
    const char* baseB = (const char*)BsW;
    int sub  = t & 7;
    int grp  = (t >> 3) & 1;
    int soff = sub * 16;
    int node = blockIdx.x * 16 + (t >> 4);
    int cnt = deg[node];
    int beg = row_ptr[node];
    float di = dis[node];

    f32x2 A0, A1, A2, A3;
    if (grp == 0) {
        uint4 su = *(const uint4*)(baseB + ((size_t)node * 128 + soff));
        A0 = up2(su.x); A1 = up2(su.y); A2 = up2(su.z); A3 = up2(su.w);
    } else {
        A0 = A1 = A2 = A3 = f32x2{0.f, 0.f};
    }

    int h  = min(cnt, ((cnt >> 1) + 1) & ~1);
    int jb = beg + (grp ? h : 0);
    int je = jb + (grp ? (cnt - h) : h);
    for (; jb + 4 <= je; jb += 4) {
        int2 sa = *(const int2*)&srt[jb];
        int2 sb = *(const int2*)&srt[jb + 2];
        uint4 g0 = *(const uint4*)(baseB + (sa.x + soff));
        uint4 g1 = *(const uint4*)(baseB + (sa.y + soff));
        uint4 g2 = *(const uint4*)(baseB + (sb.x + soff));
        uint4 g3 = *(const uint4*)(baseB + (sb.y + soff));
        A0 = A0 + (up2(g0.x) + up2(g1.x)) + (up2(g2.x) + up2(g3.x));
        A1 = A1 + (up2(g0.y) + up2(g1.y)) + (up2(g2.y) + up2(g3.y));
        A2 = A2 + (up2(g0.z) + up2(g1.z)) + (up2(g2.z) + up2(g3.z));
        A3 = A3 + (up2(g0.w) + up2(g1.w)) + (up2(g2.w) + up2(g3.w));
    }
    for (; jb + 2 <= je; jb += 2) {
        int2 sa = *(const int2*)&srt[jb];
        uint4 g0 = *(const uint4*)(baseB + (sa.x + soff));
        uint4 g1 = *(const uint4*)(baseB + (sa.y + soff));
        A0 = A0 + up2(g0.x) + up2(g1.x);
        A1 = A1 + up2(g0.y) + up2(g1.y);
        A2 = A2 + up2(g0.z) + up2(g1.z);
        A3 = A3 + up2(g0.w) + up2(g1.w);
    }
    if (jb < je) {
        int sa = srt[jb];
        uint4 g0 = *(const uint4*)(baseB + (sa + soff));
        A0 = A0 + up2(g0.x);
        A1 = A1 + up2(g0.y);
        A2 = A2 + up2(g0.z);
        A3 = A3 + up2(g0.w);
    }
    float a0 = A0.x, a1 = A0.y, a2 = A1.x, a3 = A1.y;
    float a4 = A2.x, a5 = A2.y, a6 = A3.x, a7 = A3.y;
    a0 += __shfl_xor(a0, 8, 64); a1 += __shfl_xor(a1, 8, 64);
    a2 += __shfl_xor(a2, 8, 64); a3 += __shfl_xor(a3, 8, 64);
    a4 += __shfl_xor(a4, 8, 64); a5 += __shfl_xor(a5, 8, 64);
    a6 += __shfl_xor(a6, 8, 64); a7 += __shfl_xor(a7, 8, 64);

    float4 bb0 = ((const float4*)bias)[2 * sub];
    float4 bb1 = ((const float4*)bias)[2 * sub + 1];
    float4 o;
    if (grp == 0) {
        o.x = fmaf(di, a0, bb0.x);
        o.y = fmaf(di, a1, bb0.y);
        o.z = fmaf(di, a2, bb0.z);
        o.w = fmaf(di, a3, bb0.w);
        ((float4*)outp)[(size_t)node * 16 + 2 * sub] = o;
    } else {
        o.x = fmaf(di, a4, bb1.x);
        o.y = fmaf(di, a5, bb1.y);
        o.z = fmaf(di, a6, bb1.z);
        o.w = fmaf(di, a7, bb1.w);
        ((float4*)outp)[(size_t)node * 16 + 2 * sub + 1] = o;
    }
}

extern "C" void kernel_launch(void* const* d_in, const int* in_sizes, int n_in,
                              void* d_out, int out_size, void* d_ws, size_t ws_size,
                              hipStream_t stream) {
    const float* x  = (const float*)d_in[0];
    const int*   ei = (const int*)d_in[1];   // [2,E]: src = ei[0:E], dst = ei[E:2E]
    const float* W1 = (const float*)d_in[2];
    const float* b1 = (const float*)d_in[3];
    const float* W2 = (const float*)d_in[4];
    const float* b2 = (const float*)d_in[5];
    float* out = (float*)d_out;
    int E = in_sizes[1] / 2;
    const int* src = ei;
    const int* dst = ei + E;

    int*      ws_i    = (int*)d_ws;
    int*      cursor  = ws_i + O_CURSOR;
    int*      row_ptr = ws_i + O_ROWPTR;
    int*      deg     = ws_i + O_DEG;
    float*    dis     = (float*)(ws_i + O_DIS);
    unsigned* packed  = (unsigned*)(ws_i + O_PACKED);
    int*      srt     = ws_i + O_SRT;
    unsigned* Ah      = (unsigned*)(ws_i + O_AH);
    unsigned* Bh      = (unsigned*)(ws_i + O_BH);
    unsigned* w2f     = (unsigned*)(ws_i + O_W2F);

    int nbp = (E + TILE - 1) / TILE;

    (void)hipMemsetAsync(cursor, 0, NBUCK * sizeof(int), stream);
    // K1: binpack (first nbp blocks) || MFMA gemm1 blocks [0, G1A) || W2 prep
    pre_gemm1<<<nbp + G1A + 1, 512, 0, stream>>>(src, dst, E, nbp, cursor, packed,
                                                 x, W1, Ah, W2, w2f);
    // K2: node_sort (first NBUCK blocks) || MFMA gemm1 blocks [G1A, NBLKG)
    sort_gemm1<<<NBUCK + (NBLKG - G1A), 512, 0, stream>>>(packed, cursor, row_ptr,
                                                          deg, dis, srt, x, W1, Ah);
    // K3: layer-1 aggregate + ReLU + fused layer-2 MFMA gemm -> bf16 Bh
    agg1_gemm2<<<NN / 16, 256, 0, stream>>>(Ah, row_ptr, deg, srt,
                                            dis, b1, w2f, Bh);
    // K4: layer-2 aggregate -> f32 out
    agg_out<<<NN / 16, 256, 0, stream>>>(Bh, row_ptr, deg, srt,
                                         dis, b2, out);
}